// Round 1
// baseline (3178.220 us; speedup 1.0000x reference)
//
#include <hip/hip_runtime.h>
#include <math.h>

// ---------------------------------------------------------------------------
// MemTransformerLM (Transformer-XL layer) — round 1: all-fp32 correctness-first.
// Q=1024 B=4 D=1024 NH=16 DH=64 DI=4096 M=1024 K=2048
//
// Pipeline:
//  1. gemm64<0>: cat(mems,w) @ qkv_w  -> Qh[B,NH,Q,DH], Kh[B,NH,K,DH], Vh[B,NH,K,DH]
//  2. gemm64<1>: r @ r_net_w          -> Rk[NH,K,DH]
//  3. c1_kernel: c1[b,n,j]   = r_w_bias[n]·Kh[b,n,j]
//     c2_kernel: c2[n,rel]   = r_r_bias[n]·Rk[n,rel]   (padded with 0 for rel>=2048)
//  4. attn_kernel (flash, one pass, no max-subtraction — scores are O(1)):
//        S[i,j] = (q_i·k_j + q_i·r_{j-i+1023} + c1[j] + c2[j-i+1023]) / 8
//        mask j>i+1024; AV = softmax(S)·V   (rel_shift folded into R indexing;
//        all shift-wrap positions are masked — verified by hand)
//  5. gemm64<2>: AV @ o_w + w -> X1 ; ln_kernel(X1, ln1)
//  6. gemm64<3>: relu(X1 @ ff_w1 + b1) -> H  (H aliases dead Kh+Vh)
//  7. gemm64<4>: X1 + H @ ff_w2 + b2 -> out ; ln_kernel(out, ln2)
// ---------------------------------------------------------------------------

#define QLEN 1024
#define BSZ  4
#define DMODEL 1024
#define NHEAD 16
#define DHEAD 64
#define DINNER 4096
#define MEMLEN 1024
#define KLEN 2048

// ---------------------------------------------------------------------------
// Generic 64x64x16-tile fp32 GEMM, 256 threads, 4x4 microtile.
// A is [M,Kdim] row-major (lda==Kdim), B is [Kdim,N] row-major.
// MODE 0: qkv   A=mems|w two-chunk, scatter into Qh(C)/Kh(outK)/Vh(outV)
// MODE 1: rproj scatter into Rk (C)
// MODE 2: oproj C = aux(w) + A@B
// MODE 3: ffn1  C = relu(A@B + aux(bias))
// MODE 4: ffn2  C = A2(residual) + A@B + aux(bias)
// ---------------------------------------------------------------------------
template<int MODE>
__global__ __launch_bounds__(256) void gemm64(
    const float* __restrict__ A, const float* __restrict__ Bm,
    float* __restrict__ C, const float* __restrict__ aux,
    const float* __restrict__ A2,
    float* __restrict__ outK, float* __restrict__ outV,
    int Kdim, int N)
{
  __shared__ float As[16][68];   // A tile transposed: As[kk][row]
  __shared__ float Bs[16][68];   // B tile natural:    Bs[kk][col]

  const int tid = threadIdx.x;
  const int tx = tid & 15, ty = tid >> 4;
  const int m0 = (int)blockIdx.y * 64, n0 = (int)blockIdx.x * 64;

  const int arow = tid >> 2, aks = (tid & 3) * 4;   // A staging: 64 rows x 16 k
  const int bkk = tid >> 4, bcs = (tid & 15) * 4;   // B staging: 16 k x 64 cols

  float acc[4][4] = {};

  for (int k0 = 0; k0 < Kdim; k0 += 16) {
    const float* ap;
    const int grow = m0 + arow;
    if (MODE == 0) {
      // cat(mems, w): rows [0,4096) from mems, [4096,8192) from w
      ap = (grow < MEMLEN * BSZ) ? (A + (size_t)grow * DMODEL)
                                 : (A2 + (size_t)(grow - MEMLEN * BSZ) * DMODEL);
    } else {
      ap = A + (size_t)grow * Kdim;
    }
    const float4 av = *(const float4*)(ap + k0 + aks);
    As[aks + 0][arow] = av.x;
    As[aks + 1][arow] = av.y;
    As[aks + 2][arow] = av.z;
    As[aks + 3][arow] = av.w;
    const float4 bv = *(const float4*)(Bm + (size_t)(k0 + bkk) * N + n0 + bcs);
    *(float4*)&Bs[bkk][bcs] = bv;
    __syncthreads();

#pragma unroll
    for (int kk = 0; kk < 16; ++kk) {
      const float4 a4 = *(const float4*)&As[kk][ty * 4];
      const float4 b4 = *(const float4*)&Bs[kk][tx * 4];
      const float aa[4] = {a4.x, a4.y, a4.z, a4.w};
      const float bb[4] = {b4.x, b4.y, b4.z, b4.w};
#pragma unroll
      for (int i = 0; i < 4; ++i)
#pragma unroll
        for (int j = 0; j < 4; ++j)
          acc[i][j] = fmaf(aa[i], bb[j], acc[i][j]);
    }
    __syncthreads();
  }

  // ---- epilogue ----
  if constexpr (MODE == 0) {
#pragma unroll
    for (int i = 0; i < 4; ++i) {
      const int row = m0 + ty * 4 + i;     // row = kk_global*BSZ + b
      const int kkg = row >> 2, b = row & 3;
#pragma unroll
      for (int j = 0; j < 4; ++j) {
        const int col = n0 + tx * 4 + j;   // [0,3072)
        const int sec = col >> 10;         // 0=q 1=k 2=v
        const int hn = (col >> 6) & 15, d = col & 63;
        const float v = acc[i][j];
        if (sec == 0) {
          if (kkg >= MEMLEN)
            C[((size_t)(b * NHEAD + hn) * QLEN + (kkg - MEMLEN)) * DHEAD + d] = v;
        } else if (sec == 1) {
          outK[((size_t)(b * NHEAD + hn) * KLEN + kkg) * DHEAD + d] = v;
        } else {
          outV[((size_t)(b * NHEAD + hn) * KLEN + kkg) * DHEAD + d] = v;
        }
      }
    }
  } else if constexpr (MODE == 1) {
#pragma unroll
    for (int i = 0; i < 4; ++i) {
      const int row = m0 + ty * 4 + i;     // rel index
#pragma unroll
      for (int j = 0; j < 4; ++j) {
        const int col = n0 + tx * 4 + j;
        const int hn = col >> 6, d = col & 63;
        C[((size_t)hn * KLEN + row) * DHEAD + d] = acc[i][j];
      }
    }
  } else {
#pragma unroll
    for (int i = 0; i < 4; ++i) {
      const int row = m0 + ty * 4 + i;
      const int cb = n0 + tx * 4;
      float4 o;
      if constexpr (MODE == 2) {
        const float4 res = *(const float4*)(aux + (size_t)row * N + cb);
        o.x = res.x + acc[i][0]; o.y = res.y + acc[i][1];
        o.z = res.z + acc[i][2]; o.w = res.w + acc[i][3];
      } else if constexpr (MODE == 3) {
        const float4 b4 = *(const float4*)(aux + cb);
        o.x = fmaxf(acc[i][0] + b4.x, 0.f); o.y = fmaxf(acc[i][1] + b4.y, 0.f);
        o.z = fmaxf(acc[i][2] + b4.z, 0.f); o.w = fmaxf(acc[i][3] + b4.w, 0.f);
      } else {  // MODE 4
        const float4 b4 = *(const float4*)(aux + cb);
        const float4 res = *(const float4*)(A2 + (size_t)row * N + cb);
        o.x = res.x + acc[i][0] + b4.x; o.y = res.y + acc[i][1] + b4.y;
        o.z = res.z + acc[i][2] + b4.z; o.w = res.w + acc[i][3] + b4.w;
      }
      *(float4*)(C + (size_t)row * N + cb) = o;
    }
  }
}

// ---------------------------------------------------------------------------
// c1[b,n,j] = r_w_bias[n] . Kh[b,n,j,:]
// ---------------------------------------------------------------------------
__global__ __launch_bounds__(256) void c1_kernel(
    const float* __restrict__ Kh, const float* __restrict__ rwb,
    float* __restrict__ C1)
{
  const int bn = blockIdx.x;           // b*16+n
  const int n = bn & 15;
  const float* kb = Kh + (size_t)bn * KLEN * DHEAD;
  const float* wb = rwb + n * DHEAD;
  for (int j = threadIdx.x; j < KLEN; j += 256) {
    const float* kr = kb + (size_t)j * DHEAD;
    float acc = 0.f;
#pragma unroll
    for (int d4 = 0; d4 < 16; ++d4) {
      const float4 kv = *(const float4*)(kr + d4 * 4);
      const float4 wv = *(const float4*)(wb + d4 * 4);
      acc += kv.x * wv.x + kv.y * wv.y + kv.z * wv.z + kv.w * wv.w;
    }
    C1[(size_t)bn * KLEN + j] = acc;
  }
}

// ---------------------------------------------------------------------------
// c2[n,rel] = r_r_bias[n] . Rk[n,rel,:]  for rel<2048, else 0 (mask padding)
// grid (12, 16): rel = bx*256+tid, n = by
// ---------------------------------------------------------------------------
__global__ __launch_bounds__(256) void c2_kernel(
    const float* __restrict__ Rk, const float* __restrict__ rrb,
    float* __restrict__ C2)
{
  const int n = blockIdx.y;
  const int rel = (int)blockIdx.x * 256 + threadIdx.x;   // [0,3072)
  float acc = 0.f;
  if (rel < KLEN) {
    const float* rr = Rk + ((size_t)n * KLEN + rel) * DHEAD;
    const float* wb = rrb + n * DHEAD;
#pragma unroll
    for (int d4 = 0; d4 < 16; ++d4) {
      const float4 kv = *(const float4*)(rr + d4 * 4);
      const float4 wv = *(const float4*)(wb + d4 * 4);
      acc += kv.x * wv.x + kv.y * wv.y + kv.z * wv.z + kv.w * wv.w;
    }
  }
  C2[(size_t)n * 3072 + rel] = acc;
}

// ---------------------------------------------------------------------------
// Flash-style relative attention. One block = 64 q-rows of one (b,n).
// LDS = exactly 64KB: Qs^T(16K) | KVs(16K: K^T then V) | Rs^T(32K, P aliases).
// No max-subtraction: scores ~N(0,0.6), max ~2-3, exp is fp32-safe.
// ---------------------------------------------------------------------------
__global__ __launch_bounds__(256) void attn_kernel(
    const float* __restrict__ Qh, const float* __restrict__ Kh,
    const float* __restrict__ Vh, const float* __restrict__ Rk,
    const float* __restrict__ C1, const float* __restrict__ C2,
    float* __restrict__ AV)
{
  __shared__ float smem[16384];          // 64 KiB
  float* const Qs  = smem;               // [d][i]   : Qs[d*64+i]
  float* const KVs = smem + 4096;        // K^T [d][j] then V [j][d]
  float* const Rs  = smem + 8192;        // R^T [d][t], t in [0,128)
  float* const Ps  = Rs;                 // P [i][j] padded row 68 (aliases Rs)

  const int tid = threadIdx.x;
  const int tx = tid & 15, ty = tid >> 4;
  const int i0 = (int)blockIdx.x * 64;
  const int bn = (int)blockIdx.y, b = bn >> 4, n = bn & 15;

  const float* __restrict__ Qb = Qh + (size_t)bn * QLEN * DHEAD;
  const float* __restrict__ Kb = Kh + (size_t)bn * KLEN * DHEAD;
  const float* __restrict__ Vb = Vh + (size_t)bn * KLEN * DHEAD;
  const float* __restrict__ Rb = Rk + (size_t)n * KLEN * DHEAD;
  const float* __restrict__ C1b = C1 + (size_t)bn * KLEN;
  const float* __restrict__ C2b = C2 + (size_t)n * 3072;

  // stage Q transposed (once per block)
#pragma unroll
  for (int it = 0; it < 4; ++it) {
    const int f = tid + it * 256;
    const int qi = f >> 4, ds = (f & 15) * 4;
    const float4 v = *(const float4*)(Qb + (size_t)(i0 + qi) * DHEAD + ds);
    Qs[(ds + 0) * 64 + qi] = v.x;
    Qs[(ds + 1) * 64 + qi] = v.y;
    Qs[(ds + 2) * 64 + qi] = v.z;
    Qs[(ds + 3) * 64 + qi] = v.w;
  }

  float O[4][4] = {};
  float rden[4] = {0.f, 0.f, 0.f, 0.f};
  const int t0m3 = 4 * (tx - ty + 15);          // aligned base of the r8 window
  const int nch = (i0 >> 6) + 17;               // chunks with any unmasked j

  for (int ch = 0; ch < nch; ++ch) {
    const int j0 = ch * 64;
    const int base = j0 - i0 + 960;             // Rs[.][t] = Rk[base+t]; base>=0

    // stage K^T
#pragma unroll
    for (int it = 0; it < 4; ++it) {
      const int f = tid + it * 256;
      const int kj = f >> 4, ds = (f & 15) * 4;
      const float4 v = *(const float4*)(Kb + (size_t)(j0 + kj) * DHEAD + ds);
      KVs[(ds + 0) * 64 + kj] = v.x;
      KVs[(ds + 1) * 64 + kj] = v.y;
      KVs[(ds + 2) * 64 + kj] = v.z;
      KVs[(ds + 3) * 64 + kj] = v.w;
    }
    // stage R^T (128 rows; rows past klen are masked anyway -> zeros)
#pragma unroll
    for (int it = 0; it < 8; ++it) {
      const int f = tid + it * 256;
      const int tr = f >> 4, ds = (f & 15) * 4;
      const int g = base + tr;
      float4 v = make_float4(0.f, 0.f, 0.f, 0.f);
      if (g < KLEN) v = *(const float4*)(Rb + (size_t)g * DHEAD + ds);
      Rs[(ds + 0) * 128 + tr] = v.x;
      Rs[(ds + 1) * 128 + tr] = v.y;
      Rs[(ds + 2) * 128 + tr] = v.z;
      Rs[(ds + 3) * 128 + tr] = v.w;
    }
    __syncthreads();

    // scores: sK = q.k, sR = q.r_rel  (4x4 microtile per thread)
    float sK[4][4] = {}, sR[4][4] = {};
#pragma unroll 4
    for (int kk = 0; kk < 64; ++kk) {
      const float4 q4 = *(const float4*)(Qs + kk * 64 + ty * 4);
      const float4 k4 = *(const float4*)(KVs + kk * 64 + tx * 4);
      const float4 r04 = *(const float4*)(Rs + kk * 128 + t0m3);
      const float4 r14 = *(const float4*)(Rs + kk * 128 + t0m3 + 4);
      const float qa[4] = {q4.x, q4.y, q4.z, q4.w};
      const float ka[4] = {k4.x, k4.y, k4.z, k4.w};
      const float ra[8] = {r04.x, r04.y, r04.z, r04.w, r14.x, r14.y, r14.z, r14.w};
#pragma unroll
      for (int ci = 0; ci < 4; ++ci)
#pragma unroll
        for (int cj = 0; cj < 4; ++cj) {
          sK[ci][cj] = fmaf(qa[ci], ka[cj], sK[ci][cj]);
          sR[ci][cj] = fmaf(qa[ci], ra[cj - ci + 3], sR[ci][cj]);
        }
    }
    __syncthreads();

    // P = exp(score) (masked -> 0) into Ps (aliases Rs); V into KVs
#pragma unroll
    for (int ci = 0; ci < 4; ++ci) {
      const int ig = i0 + ty * 4 + ci;
      float pp[4];
#pragma unroll
      for (int cj = 0; cj < 4; ++cj) {
        const int jg = j0 + tx * 4 + cj;
        const int dj = jg - ig;                 // rel-1023; mask: dj>1024
        const float s =
            (sK[ci][cj] + sR[ci][cj] + C1b[jg] + C2b[dj + 1023]) * 0.125f;
        const float p = (dj <= 1024) ? __expf(s) : 0.f;
        pp[cj] = p;
        rden[ci] += p;
      }
      *(float4*)(Ps + (ty * 4 + ci) * 68 + tx * 4) =
          make_float4(pp[0], pp[1], pp[2], pp[3]);
    }
#pragma unroll
    for (int it = 0; it < 4; ++it) {
      const int f = tid + it * 256;
      const int vj = f >> 4, ds = (f & 15) * 4;
      const float4 v = *(const float4*)(Vb + (size_t)(j0 + vj) * DHEAD + ds);
      *(float4*)(KVs + vj * 64 + ds) = v;
    }
    __syncthreads();

    // O += P @ V
#pragma unroll 4
    for (int jg4 = 0; jg4 < 16; ++jg4) {
      float pa[4][4], va[4][4];
#pragma unroll
      for (int ci = 0; ci < 4; ++ci) {
        const float4 p4 = *(const float4*)(Ps + (ty * 4 + ci) * 68 + jg4 * 4);
        pa[ci][0] = p4.x; pa[ci][1] = p4.y; pa[ci][2] = p4.z; pa[ci][3] = p4.w;
      }
#pragma unroll
      for (int cj = 0; cj < 4; ++cj) {
        const float4 v4 = *(const float4*)(KVs + (jg4 * 4 + cj) * 64 + tx * 4);
        va[cj][0] = v4.x; va[cj][1] = v4.y; va[cj][2] = v4.z; va[cj][3] = v4.w;
      }
#pragma unroll
      for (int ci = 0; ci < 4; ++ci)
#pragma unroll
        for (int cj = 0; cj < 4; ++cj)
#pragma unroll
          for (int cd = 0; cd < 4; ++cd)
            O[ci][cd] = fmaf(pa[ci][cj], va[cj][cd], O[ci][cd]);
    }
    __syncthreads();
  }

  // reduce denominator across the 16 tx lanes (all in the same wave per ty)
#pragma unroll
  for (int m = 1; m < 16; m <<= 1) {
#pragma unroll
    for (int ci = 0; ci < 4; ++ci)
      rden[ci] += __shfl_xor(rden[ci], m, 64);
  }

  // normalize and write AV[q*BSZ+b][n*64+d]
#pragma unroll
  for (int ci = 0; ci < 4; ++ci) {
    const float inv = 1.f / rden[ci];
    const int ig = i0 + ty * 4 + ci;
    const float4 o = make_float4(O[ci][0] * inv, O[ci][1] * inv,
                                 O[ci][2] * inv, O[ci][3] * inv);
    *(float4*)(AV + ((size_t)ig * BSZ + b) * DMODEL + n * DHEAD + tx * 4) = o;
  }
}

// ---------------------------------------------------------------------------
// In-place LayerNorm over rows of 1024. One block (256 thr) per row.
// ---------------------------------------------------------------------------
__global__ __launch_bounds__(256) void ln_kernel(
    float* __restrict__ X, const float* __restrict__ gw,
    const float* __restrict__ bw)
{
  const int row = blockIdx.x, tid = threadIdx.x;
  float* rp = X + (size_t)row * DMODEL;
  const float4 x = *(const float4*)(rp + tid * 4);
  float s = x.x + x.y + x.z + x.w;
  float q = x.x * x.x + x.y * x.y + x.z * x.z + x.w * x.w;
#pragma unroll
  for (int m = 1; m < 64; m <<= 1) {
    s += __shfl_xor(s, m, 64);
    q += __shfl_xor(q, m, 64);
  }
  __shared__ float ss[4], sq[4];
  if ((tid & 63) == 0) { ss[tid >> 6] = s; sq[tid >> 6] = q; }
  __syncthreads();
  s = ss[0] + ss[1] + ss[2] + ss[3];
  q = sq[0] + sq[1] + sq[2] + sq[3];
  const float mu = s * (1.f / DMODEL);
  const float var = q * (1.f / DMODEL) - mu * mu;
  const float rstd = rsqrtf(var + 1e-5f);
  const float4 g4 = *(const float4*)(gw + tid * 4);
  const float4 b4 = *(const float4*)(bw + tid * 4);
  float4 y;
  y.x = (x.x - mu) * rstd * g4.x + b4.x;
  y.y = (x.y - mu) * rstd * g4.y + b4.y;
  y.z = (x.z - mu) * rstd * g4.z + b4.z;
  y.w = (x.w - mu) * rstd * g4.w + b4.w;
  *(float4*)(rp + tid * 4) = y;
}

// ---------------------------------------------------------------------------
extern "C" void kernel_launch(void* const* d_in, const int* in_sizes, int n_in,
                              void* d_out, int out_size, void* d_ws,
                              size_t ws_size, hipStream_t stream)
{
  const float* w       = (const float*)d_in[0];
  const float* r       = (const float*)d_in[1];
  const float* mems    = (const float*)d_in[2];
  const float* qkv_w   = (const float*)d_in[3];
  const float* r_net_w = (const float*)d_in[4];
  const float* o_w     = (const float*)d_in[5];
  const float* r_w_bias= (const float*)d_in[6];
  const float* r_r_bias= (const float*)d_in[7];
  const float* ln1_g   = (const float*)d_in[8];
  const float* ln1_b   = (const float*)d_in[9];
  const float* ff_w1   = (const float*)d_in[10];
  const float* ff_b1   = (const float*)d_in[11];
  const float* ff_w2   = (const float*)d_in[12];
  const float* ff_b2   = (const float*)d_in[13];
  const float* ln2_g   = (const float*)d_in[14];
  const float* ln2_b   = (const float*)d_in[15];
  float* out = (float*)d_out;

  // workspace carve-up (floats). H aliases Kh+Vh (dead after attention).
  float* wsf = (float*)d_ws;
  float* Qh = wsf;                       // 4,194,304
  float* Kh = Qh + 4194304;              // 8,388,608
  float* Vh = Kh + 8388608;              // 8,388,608
  float* Rk = Vh + 8388608;              // 2,097,152
  float* AV = Rk + 2097152;              // 4,194,304
  float* X1 = AV + 4194304;              // 4,194,304
  float* C1 = X1 + 4194304;              //   131,072
  float* C2 = C1 + 131072;               //    49,152
  float* H  = Kh;                        // 16,777,216 (aliases Kh+Vh exactly)

  const dim3 blk(256);

  // 1. QKV projection: [8192,1024]@[1024,3072]
  gemm64<0><<<dim3(48, 128), blk, 0, stream>>>(
      mems, qkv_w, Qh, nullptr, w, Kh, Vh, DMODEL, 3 * DMODEL);
  // 2. R projection: [2048,1024]@[1024,1024]
  gemm64<1><<<dim3(16, 32), blk, 0, stream>>>(
      r, r_net_w, Rk, nullptr, nullptr, nullptr, nullptr, DMODEL, DMODEL);
  // 3. bias-dot precomputes
  c1_kernel<<<dim3(64), blk, 0, stream>>>(Kh, r_w_bias, C1);
  c2_kernel<<<dim3(12, 16), blk, 0, stream>>>(Rk, r_r_bias, C2);
  // 4. fused relative attention
  attn_kernel<<<dim3(16, 64), blk, 0, stream>>>(Qh, Kh, Vh, Rk, C1, C2, AV);
  // 5. output projection + residual, then LN1 (in place)
  gemm64<2><<<dim3(16, 64), blk, 0, stream>>>(
      AV, o_w, X1, w, nullptr, nullptr, nullptr, DMODEL, DMODEL);
  ln_kernel<<<dim3(4096), blk, 0, stream>>>(X1, ln1_g, ln1_b);
  // 6. FFN up + relu
  gemm64<3><<<dim3(64, 64), blk, 0, stream>>>(
      X1, ff_w1, H, ff_b1, nullptr, nullptr, nullptr, DMODEL, DINNER);
  // 7. FFN down + residual + bias, then LN2 (in place on d_out)
  gemm64<4><<<dim3(16, 64), blk, 0, stream>>>(
      H, ff_w2, out, ff_b2, X1, nullptr, nullptr, DINNER, DMODEL);
  ln_kernel<<<dim3(4096), blk, 0, stream>>>(out, ln2_g, ln2_b);

  (void)in_sizes; (void)n_in; (void)out_size; (void)ws_size;
}

// Round 2
// 1779.295 us; speedup vs baseline: 1.7862x; 1.7862x over previous
//
#include <hip/hip_runtime.h>
#include <math.h>

// ---------------------------------------------------------------------------
// MemTransformerLM (Transformer-XL layer) — round 2: bf16 MFMA for all GEMMs.
// Q=1024 B=4 D=1024 NH=16 DH=64 DI=4096 M=1024 K=2048
//
//  casts:   mems|w -> Xcat bf16; r -> Rb16; weights -> W*_t bf16 TRANSPOSED [N][K]
//  mgemm<0>: Xcat @ Wqkv_t^T -> Qh,Kh,Vh (fp32, head-split scatter)
//  mgemm<1>: Rb16 @ Wr_t^T   -> Rk (fp32)
//  c1/c2:    bias-dot precomputes (fp32, unchanged)
//  attn:     fp32 flash rel-attention (unchanged math) -> AVb bf16
//  mgemm<2>: AVb @ Wo_t^T + w -> X1 fp32 ; ln1 (writes X1 fp32 + X1b bf16)
//  mgemm<3>: relu(X1b @ W1_t^T + b1) -> H bf16   (H aliases Kh)
//  mgemm<4>: X1 + H @ W2_t^T + b2 -> out fp32 ; ln2
//
// MFMA template: 128x128 tile, BK=32, 4 waves (2x2 of 64x64), 16x16x32 bf16,
// global_load_lds width=16 staging, XOR-swizzled LDS chunks (bank-balanced
// ds_read_b128), fp32 accum. Fragment layouts per learn_hip m89/m91:
//   A: A[m=lane&15][k=(lane>>4)*8+j]   B: B[k=(lane>>4)*8+j][n=lane&15]
//   C/D: col=lane&15, row=(lane>>4)*4+reg
// ---------------------------------------------------------------------------

#define QLEN 1024
#define BSZ  4
#define DMODEL 1024
#define NHEAD 16
#define DHEAD 64
#define DINNER 4096
#define MEMLEN 1024
#define KLEN 2048

typedef __attribute__((ext_vector_type(8))) short short8;
typedef __attribute__((ext_vector_type(4))) short short4_t;
typedef __attribute__((ext_vector_type(4))) float f32x4;

__device__ __forceinline__ unsigned short f2bf(float x) {
  union { float f; unsigned u; } cv; cv.f = x;
  const unsigned u = cv.u;
  return (unsigned short)((u + 0x7FFFu + ((u >> 16) & 1u)) >> 16);
}

__device__ __forceinline__ void gload16(const void* g, void* l) {
  __builtin_amdgcn_global_load_lds(
      (const __attribute__((address_space(1))) unsigned int*)g,
      (__attribute__((address_space(3))) unsigned int*)l, 16, 0, 0);
}

// LDS chunk index for (row, kchunk) with XOR swizzle (bank-balance b128 reads)
__device__ __forceinline__ int chidx(int row, int kc) {
  return row * 4 + (kc ^ ((row >> 1) & 3));
}

// ---------------------------------------------------------------------------
// bf16 MFMA GEMM: C[M,N] = A[M,K] @ Bt[N,K]^T  (A,Bt bf16 row-major, lda=ldb=K)
// MODE 0: qkv scatter -> C(Qh), outK(Kh), outV(Vh), all fp32
// MODE 1: rproj scatter -> C(Rk) fp32
// MODE 2: C fp32 = acc + res[row,col]
// MODE 3: Cb bf16 = relu(acc + aux[col])
// MODE 4: C fp32 = acc + aux[col] + res[row,col]
// ---------------------------------------------------------------------------
template<int MODE>
__global__ __launch_bounds__(256) void mgemm(
    const unsigned short* __restrict__ A, const unsigned short* __restrict__ Bt,
    float* __restrict__ C, unsigned short* __restrict__ Cb,
    const float* __restrict__ aux, const float* __restrict__ res,
    float* __restrict__ outK, float* __restrict__ outV,
    int Kdim, int N)
{
  __shared__ __align__(16) char smem[16384];   // A 8KB | B 8KB

  const int tid = threadIdx.x;
  const int lane = tid & 63, wv = tid >> 6;
  const int m0 = (int)blockIdx.y * 128, n0 = (int)blockIdx.x * 128;

  // ---- staging pointers: 4 chunks of 16B per thread per K-iter ----
  const unsigned short *gA0, *gA1, *gB0, *gB1;
  {
    int c = tid, m = c >> 2, kc = (c & 3) ^ ((m >> 1) & 3);
    gA0 = A + (size_t)(m0 + m) * Kdim + kc * 8;
    c = 256 + tid; m = c >> 2; kc = (c & 3) ^ ((m >> 1) & 3);
    gA1 = A + (size_t)(m0 + m) * Kdim + kc * 8;
    c = tid; int n = c >> 2; kc = (c & 3) ^ ((n >> 1) & 3);
    gB0 = Bt + (size_t)(n0 + n) * Kdim + kc * 8;
    c = 256 + tid; n = c >> 2; kc = (c & 3) ^ ((n >> 1) & 3);
    gB1 = Bt + (size_t)(n0 + n) * Kdim + kc * 8;
  }
  char* const lds0 = smem + (tid & 192) * 16;  // wv*1024, wave-uniform

  // ---- fragment LDS byte offsets ----
  const int fr = lane & 15, kq = lane >> 4;
  int aoff[4], boff[4];
#pragma unroll
  for (int t = 0; t < 4; ++t) {
    const int ra = (wv & 1) * 64 + t * 16 + fr;
    aoff[t] = chidx(ra, kq) * 16;
    const int rb = (wv >> 1) * 64 + t * 16 + fr;
    boff[t] = 8192 + chidx(rb, kq) * 16;
  }

  f32x4 acc[4][4] = {};

  for (int k0 = 0; k0 < Kdim; k0 += 32) {
    gload16(gA0, lds0);
    gload16(gA1, lds0 + 4096);
    gload16(gB0, lds0 + 8192);
    gload16(gB1, lds0 + 12288);
    gA0 += 32; gA1 += 32; gB0 += 32; gB1 += 32;
    __syncthreads();

    short8 af[4], bf[4];
#pragma unroll
    for (int t = 0; t < 4; ++t) af[t] = *(const short8*)(smem + aoff[t]);
#pragma unroll
    for (int t = 0; t < 4; ++t) bf[t] = *(const short8*)(smem + boff[t]);
#pragma unroll
    for (int i = 0; i < 4; ++i)
#pragma unroll
      for (int j = 0; j < 4; ++j)
        acc[i][j] = __builtin_amdgcn_mfma_f32_16x16x32_bf16(
            af[i], bf[j], acc[i][j], 0, 0, 0);
    __syncthreads();
  }

  // ---- epilogue ----
  const int rbase = m0 + (wv & 1) * 64 + (lane >> 4) * 4;
  const int cbase = n0 + (wv >> 1) * 64 + (lane & 15);
#pragma unroll
  for (int i = 0; i < 4; ++i) {
#pragma unroll
    for (int r = 0; r < 4; ++r) {
      const int grow = rbase + i * 16 + r;
#pragma unroll
      for (int j = 0; j < 4; ++j) {
        const int gcol = cbase + j * 16;
        const float v = acc[i][j][r];
        if constexpr (MODE == 0) {
          const int kkg = grow >> 2, b = grow & 3;
          const int sec = gcol >> 10, hn = (gcol >> 6) & 15, d = gcol & 63;
          if (sec == 0) {
            if (kkg >= MEMLEN)
              C[((size_t)(b * NHEAD + hn) * QLEN + (kkg - MEMLEN)) * DHEAD + d] = v;
          } else if (sec == 1) {
            outK[((size_t)(b * NHEAD + hn) * KLEN + kkg) * DHEAD + d] = v;
          } else {
            outV[((size_t)(b * NHEAD + hn) * KLEN + kkg) * DHEAD + d] = v;
          }
        } else if constexpr (MODE == 1) {
          const int hn = gcol >> 6, d = gcol & 63;
          C[((size_t)hn * KLEN + grow) * DHEAD + d] = v;
        } else if constexpr (MODE == 2) {
          C[(size_t)grow * N + gcol] = v + res[(size_t)grow * N + gcol];
        } else if constexpr (MODE == 3) {
          Cb[(size_t)grow * N + gcol] = f2bf(fmaxf(v + aux[gcol], 0.f));
        } else {  // MODE 4
          C[(size_t)grow * N + gcol] = v + aux[gcol] + res[(size_t)grow * N + gcol];
        }
      }
    }
  }
}

// ---------------------------------------------------------------------------
// elementwise fp32 -> bf16 cast (8 elems/thread, 16B stores)
// ---------------------------------------------------------------------------
__global__ __launch_bounds__(256) void cast_bf16(
    const float* __restrict__ in, unsigned short* __restrict__ out)
{
  const size_t i = ((size_t)blockIdx.x * 256 + threadIdx.x) * 8;
  const float4 a = *(const float4*)(in + i);
  const float4 b = *(const float4*)(in + i + 4);
  short8 v;
  v[0] = (short)f2bf(a.x); v[1] = (short)f2bf(a.y);
  v[2] = (short)f2bf(a.z); v[3] = (short)f2bf(a.w);
  v[4] = (short)f2bf(b.x); v[5] = (short)f2bf(b.y);
  v[6] = (short)f2bf(b.z); v[7] = (short)f2bf(b.w);
  *(short8*)(out + i) = v;
}

// ---------------------------------------------------------------------------
// transpose + cast: in fp32 [R][C] -> out bf16 [C][R]. grid (C/64, R/64).
// ---------------------------------------------------------------------------
__global__ __launch_bounds__(256) void transpose_cast(
    const float* __restrict__ in, unsigned short* __restrict__ out,
    int R, int C)
{
  __shared__ float t[64][65];
  const int r0 = (int)blockIdx.y * 64, c0 = (int)blockIdx.x * 64;
  const int tid = threadIdx.x;
  const int rr = tid >> 4, cc = (tid & 15) * 4;
#pragma unroll
  for (int it = 0; it < 4; ++it) {
    const int r = rr + it * 16;
    const float4 v = *(const float4*)(in + (size_t)(r0 + r) * C + c0 + cc);
    t[r][cc] = v.x; t[r][cc + 1] = v.y; t[r][cc + 2] = v.z; t[r][cc + 3] = v.w;
  }
  __syncthreads();
  const int oc = tid >> 2, ob = (tid & 3) * 16;
#pragma unroll
  for (int j4 = 0; j4 < 4; ++j4) {
    short4_t o;
#pragma unroll
    for (int j = 0; j < 4; ++j) o[j] = (short)f2bf(t[ob + j4 * 4 + j][oc]);
    *(short4_t*)(out + (size_t)(c0 + oc) * R + r0 + ob + j4 * 4) = o;
  }
}

// ---------------------------------------------------------------------------
// c1[b,n,j] = r_w_bias[n] . Kh[b,n,j,:]
// ---------------------------------------------------------------------------
__global__ __launch_bounds__(256) void c1_kernel(
    const float* __restrict__ Kh, const float* __restrict__ rwb,
    float* __restrict__ C1)
{
  const int bn = blockIdx.x;
  const int n = bn & 15;
  const float* kb = Kh + (size_t)bn * KLEN * DHEAD;
  const float* wb = rwb + n * DHEAD;
  for (int j = threadIdx.x; j < KLEN; j += 256) {
    const float* kr = kb + (size_t)j * DHEAD;
    float acc = 0.f;
#pragma unroll
    for (int d4 = 0; d4 < 16; ++d4) {
      const float4 kv = *(const float4*)(kr + d4 * 4);
      const float4 wv = *(const float4*)(wb + d4 * 4);
      acc += kv.x * wv.x + kv.y * wv.y + kv.z * wv.z + kv.w * wv.w;
    }
    C1[(size_t)bn * KLEN + j] = acc;
  }
}

// ---------------------------------------------------------------------------
// c2[n,rel] = r_r_bias[n] . Rk[n,rel,:]  for rel<2048, else 0
// ---------------------------------------------------------------------------
__global__ __launch_bounds__(256) void c2_kernel(
    const float* __restrict__ Rk, const float* __restrict__ rrb,
    float* __restrict__ C2)
{
  const int n = blockIdx.y;
  const int rel = (int)blockIdx.x * 256 + threadIdx.x;
  float acc = 0.f;
  if (rel < KLEN) {
    const float* rr = Rk + ((size_t)n * KLEN + rel) * DHEAD;
    const float* wb = rrb + n * DHEAD;
#pragma unroll
    for (int d4 = 0; d4 < 16; ++d4) {
      const float4 kv = *(const float4*)(rr + d4 * 4);
      const float4 wv = *(const float4*)(wb + d4 * 4);
      acc += kv.x * wv.x + kv.y * wv.y + kv.z * wv.z + kv.w * wv.w;
    }
  }
  C2[(size_t)n * 3072 + rel] = acc;
}

// ---------------------------------------------------------------------------
// Flash-style relative attention (fp32, unchanged math); output bf16 AVb.
// ---------------------------------------------------------------------------
__global__ __launch_bounds__(256) void attn_kernel(
    const float* __restrict__ Qh, const float* __restrict__ Kh,
    const float* __restrict__ Vh, const float* __restrict__ Rk,
    const float* __restrict__ C1, const float* __restrict__ C2,
    unsigned short* __restrict__ AVb)
{
  __shared__ float smem[16384];
  float* const Qs  = smem;
  float* const KVs = smem + 4096;
  float* const Rs  = smem + 8192;
  float* const Ps  = Rs;

  const int tid = threadIdx.x;
  const int tx = tid & 15, ty = tid >> 4;
  const int i0 = (int)blockIdx.x * 64;
  const int bn = (int)blockIdx.y, b = bn >> 4, n = bn & 15;

  const float* __restrict__ Qb = Qh + (size_t)bn * QLEN * DHEAD;
  const float* __restrict__ Kb = Kh + (size_t)bn * KLEN * DHEAD;
  const float* __restrict__ Vb = Vh + (size_t)bn * KLEN * DHEAD;
  const float* __restrict__ Rb = Rk + (size_t)n * KLEN * DHEAD;
  const float* __restrict__ C1b = C1 + (size_t)bn * KLEN;
  const float* __restrict__ C2b = C2 + (size_t)n * 3072;

#pragma unroll
  for (int it = 0; it < 4; ++it) {
    const int f = tid + it * 256;
    const int qi = f >> 4, ds = (f & 15) * 4;
    const float4 v = *(const float4*)(Qb + (size_t)(i0 + qi) * DHEAD + ds);
    Qs[(ds + 0) * 64 + qi] = v.x;
    Qs[(ds + 1) * 64 + qi] = v.y;
    Qs[(ds + 2) * 64 + qi] = v.z;
    Qs[(ds + 3) * 64 + qi] = v.w;
  }

  float O[4][4] = {};
  float rden[4] = {0.f, 0.f, 0.f, 0.f};
  const int t0m3 = 4 * (tx - ty + 15);
  const int nch = (i0 >> 6) + 17;

  for (int ch = 0; ch < nch; ++ch) {
    const int j0 = ch * 64;
    const int base = j0 - i0 + 960;

#pragma unroll
    for (int it = 0; it < 4; ++it) {
      const int f = tid + it * 256;
      const int kj = f >> 4, ds = (f & 15) * 4;
      const float4 v = *(const float4*)(Kb + (size_t)(j0 + kj) * DHEAD + ds);
      KVs[(ds + 0) * 64 + kj] = v.x;
      KVs[(ds + 1) * 64 + kj] = v.y;
      KVs[(ds + 2) * 64 + kj] = v.z;
      KVs[(ds + 3) * 64 + kj] = v.w;
    }
#pragma unroll
    for (int it = 0; it < 8; ++it) {
      const int f = tid + it * 256;
      const int tr = f >> 4, ds = (f & 15) * 4;
      const int g = base + tr;
      float4 v = make_float4(0.f, 0.f, 0.f, 0.f);
      if (g < KLEN) v = *(const float4*)(Rb + (size_t)g * DHEAD + ds);
      Rs[(ds + 0) * 128 + tr] = v.x;
      Rs[(ds + 1) * 128 + tr] = v.y;
      Rs[(ds + 2) * 128 + tr] = v.z;
      Rs[(ds + 3) * 128 + tr] = v.w;
    }
    __syncthreads();

    float sK[4][4] = {}, sR[4][4] = {};
#pragma unroll 4
    for (int kk = 0; kk < 64; ++kk) {
      const float4 q4 = *(const float4*)(Qs + kk * 64 + ty * 4);
      const float4 k4 = *(const float4*)(KVs + kk * 64 + tx * 4);
      const float4 r04 = *(const float4*)(Rs + kk * 128 + t0m3);
      const float4 r14 = *(const float4*)(Rs + kk * 128 + t0m3 + 4);
      const float qa[4] = {q4.x, q4.y, q4.z, q4.w};
      const float ka[4] = {k4.x, k4.y, k4.z, k4.w};
      const float ra[8] = {r04.x, r04.y, r04.z, r04.w, r14.x, r14.y, r14.z, r14.w};
#pragma unroll
      for (int ci = 0; ci < 4; ++ci)
#pragma unroll
        for (int cj = 0; cj < 4; ++cj) {
          sK[ci][cj] = fmaf(qa[ci], ka[cj], sK[ci][cj]);
          sR[ci][cj] = fmaf(qa[ci], ra[cj - ci + 3], sR[ci][cj]);
        }
    }
    __syncthreads();

#pragma unroll
    for (int ci = 0; ci < 4; ++ci) {
      const int ig = i0 + ty * 4 + ci;
      float pp[4];
#pragma unroll
      for (int cj = 0; cj < 4; ++cj) {
        const int jg = j0 + tx * 4 + cj;
        const int dj = jg - ig;
        const float s =
            (sK[ci][cj] + sR[ci][cj] + C1b[jg] + C2b[dj + 1023]) * 0.125f;
        const float p = (dj <= 1024) ? __expf(s) : 0.f;
        pp[cj] = p;
        rden[ci] += p;
      }
      *(float4*)(Ps + (ty * 4 + ci) * 68 + tx * 4) =
          make_float4(pp[0], pp[1], pp[2], pp[3]);
    }
#pragma unroll
    for (int it = 0; it < 4; ++it) {
      const int f = tid + it * 256;
      const int vj = f >> 4, ds = (f & 15) * 4;
      const float4 v = *(const float4*)(Vb + (size_t)(j0 + vj) * DHEAD + ds);
      *(float4*)(KVs + vj * 64 + ds) = v;
    }
    __syncthreads();

#pragma unroll 4
    for (int jg4 = 0; jg4 < 16; ++jg4) {
      float pa[4][4], va[4][4];
#pragma unroll
      for (int ci = 0; ci < 4; ++ci) {
        const float4 p4 = *(const float4*)(Ps + (ty * 4 + ci) * 68 + jg4 * 4);
        pa[ci][0] = p4.x; pa[ci][1] = p4.y; pa[ci][2] = p4.z; pa[ci][3] = p4.w;
      }
#pragma unroll
      for (int cj = 0; cj < 4; ++cj) {
        const float4 v4 = *(const float4*)(KVs + (jg4 * 4 + cj) * 64 + tx * 4);
        va[cj][0] = v4.x; va[cj][1] = v4.y; va[cj][2] = v4.z; va[cj][3] = v4.w;
      }
#pragma unroll
      for (int ci = 0; ci < 4; ++ci)
#pragma unroll
        for (int cj = 0; cj < 4; ++cj)
#pragma unroll
          for (int cd = 0; cd < 4; ++cd)
            O[ci][cd] = fmaf(pa[ci][cj], va[cj][cd], O[ci][cd]);
    }
    __syncthreads();
  }

#pragma unroll
  for (int m = 1; m < 16; m <<= 1) {
#pragma unroll
    for (int ci = 0; ci < 4; ++ci)
      rden[ci] += __shfl_xor(rden[ci], m, 64);
  }

#pragma unroll
  for (int ci = 0; ci < 4; ++ci) {
    const float inv = 1.f / rden[ci];
    const int ig = i0 + ty * 4 + ci;
    short4_t o;
    o[0] = (short)f2bf(O[ci][0] * inv);
    o[1] = (short)f2bf(O[ci][1] * inv);
    o[2] = (short)f2bf(O[ci][2] * inv);
    o[3] = (short)f2bf(O[ci][3] * inv);
    *(short4_t*)(AVb + ((size_t)ig * BSZ + b) * DMODEL + n * DHEAD + tx * 4) = o;
  }
}

// ---------------------------------------------------------------------------
// In-place LayerNorm over rows of 1024; optional bf16 copy.
// ---------------------------------------------------------------------------
__global__ __launch_bounds__(256) void ln_kernel(
    float* __restrict__ X, const float* __restrict__ gw,
    const float* __restrict__ bw, unsigned short* __restrict__ bfo)
{
  const int row = blockIdx.x, tid = threadIdx.x;
  float* rp = X + (size_t)row * DMODEL;
  const float4 x = *(const float4*)(rp + tid * 4);
  float s = x.x + x.y + x.z + x.w;
  float q = x.x * x.x + x.y * x.y + x.z * x.z + x.w * x.w;
#pragma unroll
  for (int m = 1; m < 64; m <<= 1) {
    s += __shfl_xor(s, m, 64);
    q += __shfl_xor(q, m, 64);
  }
  __shared__ float ss[4], sq[4];
  if ((tid & 63) == 0) { ss[tid >> 6] = s; sq[tid >> 6] = q; }
  __syncthreads();
  s = ss[0] + ss[1] + ss[2] + ss[3];
  q = sq[0] + sq[1] + sq[2] + sq[3];
  const float mu = s * (1.f / DMODEL);
  const float var = q * (1.f / DMODEL) - mu * mu;
  const float rstd = rsqrtf(var + 1e-5f);
  const float4 g4 = *(const float4*)(gw + tid * 4);
  const float4 b4 = *(const float4*)(bw + tid * 4);
  float4 y;
  y.x = (x.x - mu) * rstd * g4.x + b4.x;
  y.y = (x.y - mu) * rstd * g4.y + b4.y;
  y.z = (x.z - mu) * rstd * g4.z + b4.z;
  y.w = (x.w - mu) * rstd * g4.w + b4.w;
  *(float4*)(rp + tid * 4) = y;
  if (bfo) {
    short4_t o;
    o[0] = (short)f2bf(y.x); o[1] = (short)f2bf(y.y);
    o[2] = (short)f2bf(y.z); o[3] = (short)f2bf(y.w);
    *(short4_t*)(bfo + (size_t)row * DMODEL + tid * 4) = o;
  }
}

// ---------------------------------------------------------------------------
extern "C" void kernel_launch(void* const* d_in, const int* in_sizes, int n_in,
                              void* d_out, int out_size, void* d_ws,
                              size_t ws_size, hipStream_t stream)
{
  const float* w       = (const float*)d_in[0];
  const float* r       = (const float*)d_in[1];
  const float* mems    = (const float*)d_in[2];
  const float* qkv_w   = (const float*)d_in[3];
  const float* r_net_w = (const float*)d_in[4];
  const float* o_w     = (const float*)d_in[5];
  const float* r_w_bias= (const float*)d_in[6];
  const float* r_r_bias= (const float*)d_in[7];
  const float* ln1_g   = (const float*)d_in[8];
  const float* ln1_b   = (const float*)d_in[9];
  const float* ff_w1   = (const float*)d_in[10];
  const float* ff_b1   = (const float*)d_in[11];
  const float* ff_w2   = (const float*)d_in[12];
  const float* ff_b2   = (const float*)d_in[13];
  const float* ln2_g   = (const float*)d_in[14];
  const float* ln2_b   = (const float*)d_in[15];
  float* out = (float*)d_out;

  // ---- workspace carve-up ----
  float* wsf = (float*)d_ws;
  float* Qh = wsf;                       // 4,194,304 f32
  float* Kh = Qh + 4194304;              // 8,388,608
  float* Vh = Kh + 8388608;              // 8,388,608
  float* Rk = Vh + 8388608;              // 2,097,152
  float* X1 = Rk + 2097152;              // 4,194,304
  float* C1 = X1 + 4194304;              //   131,072
  float* C2 = C1 + 131072;               //    65,536 (padded)
  unsigned short* Xcat = (unsigned short*)(C2 + 65536);  // 8,388,608 sh
  unsigned short* Wqkv = Xcat + 8388608;                 // 3,145,728
  unsigned short* Wr   = Wqkv + 3145728;                 // 1,048,576
  unsigned short* Wo   = Wr + 1048576;                   // 1,048,576
  unsigned short* W1   = Wo + 1048576;                   // 4,194,304
  unsigned short* W2   = W1 + 4194304;                   // 4,194,304
  unsigned short* Rb16 = Xcat;                 // alias (Xcat dead after qkv)
  unsigned short* AVb  = Xcat + 4194304;       // alias, disjoint from Rb16
  unsigned short* X1b  = (unsigned short*)Qh;  // alias (Qh dead after attn)
  unsigned short* H    = (unsigned short*)Kh;  // alias (Kh dead after attn)

  const dim3 blk(256);

  // casts + weight transposes
  cast_bf16<<<dim3(2048), blk, 0, stream>>>(mems, Xcat);
  cast_bf16<<<dim3(2048), blk, 0, stream>>>(w, Xcat + 4194304);
  transpose_cast<<<dim3(48, 16), blk, 0, stream>>>(qkv_w, Wqkv, 1024, 3072);
  transpose_cast<<<dim3(16, 16), blk, 0, stream>>>(r_net_w, Wr, 1024, 1024);
  transpose_cast<<<dim3(16, 16), blk, 0, stream>>>(o_w, Wo, 1024, 1024);
  transpose_cast<<<dim3(64, 16), blk, 0, stream>>>(ff_w1, W1, 1024, 4096);
  transpose_cast<<<dim3(16, 64), blk, 0, stream>>>(ff_w2, W2, 4096, 1024);

  // 1. QKV: [8192,1024] @ [1024,3072]
  mgemm<0><<<dim3(24, 64), blk, 0, stream>>>(
      Xcat, Wqkv, Qh, nullptr, nullptr, nullptr, Kh, Vh, DMODEL, 3 * DMODEL);
  // 2. R projection: [2048,1024] @ [1024,1024]  (Rb16 overwrites Xcat — qkv done)
  cast_bf16<<<dim3(1024), blk, 0, stream>>>(r, Rb16);
  mgemm<1><<<dim3(8, 16), blk, 0, stream>>>(
      Rb16, Wr, Rk, nullptr, nullptr, nullptr, nullptr, nullptr, DMODEL, DMODEL);
  // 3. bias-dot precomputes
  c1_kernel<<<dim3(64), blk, 0, stream>>>(Kh, r_w_bias, C1);
  c2_kernel<<<dim3(12, 16), blk, 0, stream>>>(Rk, r_r_bias, C2);
  // 4. fused relative attention -> AVb bf16
  attn_kernel<<<dim3(16, 64), blk, 0, stream>>>(Qh, Kh, Vh, Rk, C1, C2, AVb);
  // 5. output projection + residual -> X1 fp32; LN1 (also emits X1b bf16)
  mgemm<2><<<dim3(8, 32), blk, 0, stream>>>(
      AVb, Wo, X1, nullptr, nullptr, w, nullptr, nullptr, DMODEL, DMODEL);
  ln_kernel<<<dim3(4096), blk, 0, stream>>>(X1, ln1_g, ln1_b, X1b);
  // 6. FFN up + relu -> H bf16
  mgemm<3><<<dim3(32, 32), blk, 0, stream>>>(
      X1b, W1, nullptr, H, ff_b1, nullptr, nullptr, nullptr, DMODEL, DINNER);
  // 7. FFN down + bias + residual -> out fp32; LN2
  mgemm<4><<<dim3(8, 32), blk, 0, stream>>>(
      H, W2, out, nullptr, ff_b2, X1, nullptr, nullptr, DINNER, DMODEL);
  ln_kernel<<<dim3(4096), blk, 0, stream>>>(out, ln2_g, ln2_b, nullptr);

  (void)in_sizes; (void)n_in; (void)out_size; (void)ws_size;
}

// Round 3
// 685.955 us; speedup vs baseline: 4.6333x; 2.5939x over previous
//
#include <hip/hip_runtime.h>
#include <math.h>

// ---------------------------------------------------------------------------
// MemTransformerLM (Transformer-XL layer) — round 3: MFMA flash attention.
// Q=1024 B=4 D=1024 NH=16 DH=64 DI=4096 M=1024 K=2048
//
//  casts:    mems|w -> Xcat bf16; r -> Rb16; weights -> bf16 transposed [N][K]
//  mgemm<0>: Xcat @ Wqkv^T -> Qh,Kh bf16 [bn][len][64], Vt bf16 [bn][64][2048]
//  mgemm<1>: Rb16 @ Wr^T   -> Rk bf16 [n][2048][64]
//  attn_mfma: bf16 MFMA flash rel-attention (biases folded into Q frags,
//             rel-shift as LDS gather of U=Q@R_window^T) -> AVb bf16
//  mgemm<2>: AVb @ Wo^T + w -> X1 fp32 ; ln1 (fp32 + bf16 X1b)
//  mgemm<3>: relu(X1b @ W1^T + b1) -> H bf16 (aliases Kh+Vt)
//  mgemm<4>: X1 + H @ W2^T + b2 -> out fp32 ; ln2
// ---------------------------------------------------------------------------

#define QLEN 1024
#define BSZ  4
#define DMODEL 1024
#define NHEAD 16
#define DHEAD 64
#define DINNER 4096
#define MEMLEN 1024
#define KLEN 2048

typedef __attribute__((ext_vector_type(8))) short short8;
typedef __attribute__((ext_vector_type(4))) short short4_t;
typedef __attribute__((ext_vector_type(4))) float f32x4;

__device__ __forceinline__ unsigned short f2bf(float x) {
  union { float f; unsigned u; } cv; cv.f = x;
  const unsigned u = cv.u;
  return (unsigned short)((u + 0x7FFFu + ((u >> 16) & 1u)) >> 16);
}
__device__ __forceinline__ float bf2f(unsigned short b) {
  union { unsigned u; float f; } cv; cv.u = ((unsigned)b) << 16;
  return cv.f;
}

__device__ __forceinline__ void gload16(const void* g, void* l) {
  __builtin_amdgcn_global_load_lds(
      (const __attribute__((address_space(1))) unsigned int*)g,
      (__attribute__((address_space(3))) unsigned int*)l, 16, 0, 0);
}

// 4-chunk-per-row XOR swizzle (mgemm K=32 tiles)
__device__ __forceinline__ int chidx(int row, int kc) {
  return row * 4 + (kc ^ ((row >> 1) & 3));
}

// ---------------------------------------------------------------------------
// bf16 MFMA GEMM: C[M,N] = A[M,K] @ Bt[N,K]^T. 128x128 tile, BK=32, 4 waves.
// MODE 0: qkv scatter -> Cb(Qh bf16), oK(Kh bf16), oV(Vt bf16 TRANSPOSED [d][j])
// MODE 1: rproj scatter -> Cb(Rk bf16)
// MODE 2: C fp32 = acc + res[row,col]
// MODE 3: Cb bf16 = relu(acc + aux[col])
// MODE 4: C fp32 = acc + aux[col] + res[row,col]
// ---------------------------------------------------------------------------
template<int MODE>
__global__ __launch_bounds__(256) void mgemm(
    const unsigned short* __restrict__ A, const unsigned short* __restrict__ Bt,
    float* __restrict__ C, unsigned short* __restrict__ Cb,
    const float* __restrict__ aux, const float* __restrict__ res,
    unsigned short* __restrict__ oK, unsigned short* __restrict__ oV,
    int Kdim, int N)
{
  __shared__ __align__(16) char smem[16384];   // A 8KB | B 8KB

  const int tid = threadIdx.x;
  const int lane = tid & 63, wv = tid >> 6;
  const int m0 = (int)blockIdx.y * 128, n0 = (int)blockIdx.x * 128;

  const unsigned short *gA0, *gA1, *gB0, *gB1;
  {
    int c = tid, m = c >> 2, kc = (c & 3) ^ ((m >> 1) & 3);
    gA0 = A + (size_t)(m0 + m) * Kdim + kc * 8;
    c = 256 + tid; m = c >> 2; kc = (c & 3) ^ ((m >> 1) & 3);
    gA1 = A + (size_t)(m0 + m) * Kdim + kc * 8;
    c = tid; int nn = c >> 2; kc = (c & 3) ^ ((nn >> 1) & 3);
    gB0 = Bt + (size_t)(n0 + nn) * Kdim + kc * 8;
    c = 256 + tid; nn = c >> 2; kc = (c & 3) ^ ((nn >> 1) & 3);
    gB1 = Bt + (size_t)(n0 + nn) * Kdim + kc * 8;
  }
  char* const lds0 = smem + (tid & 192) * 16;

  const int fr = lane & 15, kq = lane >> 4;
  int aoff[4], boff[4];
#pragma unroll
  for (int t = 0; t < 4; ++t) {
    const int ra = (wv & 1) * 64 + t * 16 + fr;
    aoff[t] = chidx(ra, kq) * 16;
    const int rb = (wv >> 1) * 64 + t * 16 + fr;
    boff[t] = 8192 + chidx(rb, kq) * 16;
  }

  f32x4 acc[4][4] = {};

  for (int k0 = 0; k0 < Kdim; k0 += 32) {
    gload16(gA0, lds0);
    gload16(gA1, lds0 + 4096);
    gload16(gB0, lds0 + 8192);
    gload16(gB1, lds0 + 12288);
    gA0 += 32; gA1 += 32; gB0 += 32; gB1 += 32;
    __syncthreads();

    short8 af[4], bf[4];
#pragma unroll
    for (int t = 0; t < 4; ++t) af[t] = *(const short8*)(smem + aoff[t]);
#pragma unroll
    for (int t = 0; t < 4; ++t) bf[t] = *(const short8*)(smem + boff[t]);
#pragma unroll
    for (int i = 0; i < 4; ++i)
#pragma unroll
      for (int j = 0; j < 4; ++j)
        acc[i][j] = __builtin_amdgcn_mfma_f32_16x16x32_bf16(
            af[i], bf[j], acc[i][j], 0, 0, 0);
    __syncthreads();
  }

  const int rbase = m0 + (wv & 1) * 64 + (lane >> 4) * 4;
  const int cbase = n0 + (wv >> 1) * 64 + (lane & 15);
#pragma unroll
  for (int i = 0; i < 4; ++i) {
#pragma unroll
    for (int r = 0; r < 4; ++r) {
      const int grow = rbase + i * 16 + r;
#pragma unroll
      for (int j = 0; j < 4; ++j) {
        const int gcol = cbase + j * 16;
        const float v = acc[i][j][r];
        if constexpr (MODE == 0) {
          const int kkg = grow >> 2, b2 = grow & 3;
          const int sec = gcol >> 10, hn = (gcol >> 6) & 15, d = gcol & 63;
          const unsigned short bv = f2bf(v);
          if (sec == 0) {
            if (kkg >= MEMLEN)
              Cb[((size_t)(b2 * NHEAD + hn) * QLEN + (kkg - MEMLEN)) * DHEAD + d] = bv;
          } else if (sec == 1) {
            oK[((size_t)(b2 * NHEAD + hn) * KLEN + kkg) * DHEAD + d] = bv;
          } else {  // V transposed: [bn][d][j]
            oV[((size_t)(b2 * NHEAD + hn) * DHEAD + d) * KLEN + kkg] = bv;
          }
        } else if constexpr (MODE == 1) {
          const int hn = gcol >> 6, d = gcol & 63;
          Cb[((size_t)hn * KLEN + grow) * DHEAD + d] = f2bf(v);
        } else if constexpr (MODE == 2) {
          C[(size_t)grow * N + gcol] = v + res[(size_t)grow * N + gcol];
        } else if constexpr (MODE == 3) {
          Cb[(size_t)grow * N + gcol] = f2bf(fmaxf(v + aux[gcol], 0.f));
        } else {
          C[(size_t)grow * N + gcol] = v + aux[gcol] + res[(size_t)grow * N + gcol];
        }
      }
    }
  }
}

// ---------------------------------------------------------------------------
__global__ __launch_bounds__(256) void cast_bf16(
    const float* __restrict__ in, unsigned short* __restrict__ out)
{
  const size_t i = ((size_t)blockIdx.x * 256 + threadIdx.x) * 8;
  const float4 a = *(const float4*)(in + i);
  const float4 b = *(const float4*)(in + i + 4);
  short8 v;
  v[0] = (short)f2bf(a.x); v[1] = (short)f2bf(a.y);
  v[2] = (short)f2bf(a.z); v[3] = (short)f2bf(a.w);
  v[4] = (short)f2bf(b.x); v[5] = (short)f2bf(b.y);
  v[6] = (short)f2bf(b.z); v[7] = (short)f2bf(b.w);
  *(short8*)(out + i) = v;
}

// ---------------------------------------------------------------------------
__global__ __launch_bounds__(256) void transpose_cast(
    const float* __restrict__ in, unsigned short* __restrict__ out,
    int R, int C)
{
  __shared__ float t[64][65];
  const int r0 = (int)blockIdx.y * 64, c0 = (int)blockIdx.x * 64;
  const int tid = threadIdx.x;
  const int rr = tid >> 4, cc = (tid & 15) * 4;
#pragma unroll
  for (int it = 0; it < 4; ++it) {
    const int r = rr + it * 16;
    const float4 v = *(const float4*)(in + (size_t)(r0 + r) * C + c0 + cc);
    t[r][cc] = v.x; t[r][cc + 1] = v.y; t[r][cc + 2] = v.z; t[r][cc + 3] = v.w;
  }
  __syncthreads();
  const int oc = tid >> 2, ob = (tid & 3) * 16;
#pragma unroll
  for (int j4 = 0; j4 < 4; ++j4) {
    short4_t o;
#pragma unroll
    for (int j = 0; j < 4; ++j) o[j] = (short)f2bf(t[ob + j4 * 4 + j][oc]);
    *(short4_t*)(out + (size_t)(c0 + oc) * R + r0 + ob + j4 * 4) = o;
  }
}

// ---------------------------------------------------------------------------
// MFMA flash relative attention. Block = 256 thr (4 waves), i-tile 64 for one
// (b,n); wave w owns i-strip [w*16, w*16+16). j chunks of 64.
// LDS 48KB: Ks 8K (P aliases) | Vts 8K | Rs 16K | Us 16K.
// 8-chunk rows use swizzle c' = c ^ (row&7) -> 2-way (free) ds_read_b128.
// rel_shift: U[i][t] = (q_i+rrb)·R[base_r+t], gather at t = j-i+63.
// Biases folded into per-lane Q fragments; no max-subtraction (scores O(1)).
// ---------------------------------------------------------------------------
__global__ __launch_bounds__(256) void attn_mfma(
    const unsigned short* __restrict__ Qh, const unsigned short* __restrict__ Kh,
    const unsigned short* __restrict__ Vt, const unsigned short* __restrict__ Rk,
    const float* __restrict__ rwb, const float* __restrict__ rrb,
    unsigned short* __restrict__ AVb)
{
  __shared__ __align__(16) char smem[49152];
  unsigned short* const Us = (unsigned short*)(smem + 32768);
  unsigned short* const Ps = (unsigned short*)smem;   // aliases Ks

  const int tid = threadIdx.x;
  const int lane = tid & 63, wv = tid >> 6;
  const int quad = lane >> 4, l15 = lane & 15;
  const int i0 = (int)blockIdx.x * 64;
  const int bn = (int)blockIdx.y, b = bn >> 4, n = bn & 15;

  const unsigned short* __restrict__ Qb = Qh + (size_t)bn * QLEN * DHEAD;
  const unsigned short* __restrict__ Kb = Kh + (size_t)bn * KLEN * DHEAD;
  const unsigned short* __restrict__ Vb = Vt + (size_t)bn * DHEAD * KLEN;
  const unsigned short* __restrict__ Rb = Rk + (size_t)n * KLEN * DHEAD;

  // persistent Q fragments with biases folded: qk = q + r_w_bias, qr = q + r_r_bias
  short8 qk[2], qr[2];
  {
    const int qrow = i0 + wv * 16 + l15;
    const unsigned short* qp = Qb + (size_t)qrow * DHEAD + quad * 8;
    const float* wp = rwb + n * DHEAD + quad * 8;
    const float* rp = rrb + n * DHEAD + quad * 8;
#pragma unroll
    for (int ks = 0; ks < 2; ++ks) {
      const short8 q8 = *(const short8*)(qp + ks * 32);
#pragma unroll
      for (int e = 0; e < 8; ++e) {
        const float qv = bf2f((unsigned short)q8[e]);
        qk[ks][e] = (short)f2bf(qv + wp[ks * 32 + e]);
        qr[ks][e] = (short)f2bf(qv + rp[ks * 32 + e]);
      }
    }
  }

  f32x4 O[4] = {};
  float rden[4] = {0.f, 0.f, 0.f, 0.f};
  char* const lds0 = smem + (tid & 192) * 16;
  const int nch = (i0 >> 6) + 17;

  for (int ch = 0; ch < nch; ++ch) {
    const int j0 = ch * 64;
    const int base_r = j0 - i0 + 960;   // >= 0; rows >= KLEN read pad (masked)

    __syncthreads();   // prior chunk's LDS reads complete before restage

    // ---- stage K (8KB), Vt (8KB), R (16KB) via global_load_lds ----
#pragma unroll
    for (int it = 0; it < 2; ++it) {
      const int s = it * 256 + tid;
      const int row = s >> 3, kc = (s & 7) ^ (row & 7);
      gload16(Kb + (((size_t)(j0 + row)) << 6) + kc * 8, lds0 + it * 4096);
    }
#pragma unroll
    for (int it = 0; it < 2; ++it) {
      const int s = it * 256 + tid;
      const int row = s >> 3, kc = (s & 7) ^ (row & 7);
      gload16(Vb + (((size_t)row) << 11) + j0 + kc * 8, lds0 + 8192 + it * 4096);
    }
#pragma unroll
    for (int it = 0; it < 4; ++it) {
      const int s = it * 256 + tid;
      const int row = s >> 3, kc = (s & 7) ^ (row & 7);
      gload16(Rb + (((size_t)(base_r + row)) << 6) + kc * 8,
              lds0 + 16384 + it * 4096);
    }
    __syncthreads();

    // ---- S_K = (q+rwb)·k : 4 j-tiles ----
    f32x4 sk[4];
#pragma unroll
    for (int jt = 0; jt < 4; ++jt) {
      f32x4 a = {0.f, 0.f, 0.f, 0.f};
#pragma unroll
      for (int ks = 0; ks < 2; ++ks) {
        const int frr = jt * 16 + l15;
        const int c = (ks * 4 + quad) ^ (frr & 7);
        const short8 kf = *(const short8*)(smem + (frr * 8 + c) * 16);
        a = __builtin_amdgcn_mfma_f32_16x16x32_bf16(qk[ks], kf, a, 0, 0, 0);
      }
      sk[jt] = a;
    }
    // ---- U = (q+rrb)·r window : 8 t-tiles -> LDS bf16 (wave-private strip) ----
#pragma unroll
    for (int tt = 0; tt < 8; ++tt) {
      f32x4 a = {0.f, 0.f, 0.f, 0.f};
#pragma unroll
      for (int ks = 0; ks < 2; ++ks) {
        const int frr = tt * 16 + l15;
        const int c = (ks * 4 + quad) ^ (frr & 7);
        const short8 rf = *(const short8*)(smem + 16384 + (frr * 8 + c) * 16);
        a = __builtin_amdgcn_mfma_f32_16x16x32_bf16(qr[ks], rf, a, 0, 0, 0);
      }
      const int ub = (wv * 16 + quad * 4) * 128 + tt * 16 + l15;
#pragma unroll
      for (int r = 0; r < 4; ++r) Us[ub + r * 128] = f2bf(a[r]);
    }
    __syncthreads();   // all waves' K-frag reads done before P overwrites Ks

    // ---- P = exp((S_K + U_gather) * 1/8), masked; write to Ps (A-layout) ----
#pragma unroll
    for (int jt = 0; jt < 4; ++jt) {
      const int jl = jt * 16 + l15;
#pragma unroll
      for (int r = 0; r < 4; ++r) {
        const int il = wv * 16 + quad * 4 + r;
        const int dj = (j0 + jl) - (i0 + il);
        const float uv = bf2f(Us[il * 128 + (jl - il + 63)]);
        const float s = (sk[jt][r] + uv) * 0.125f;
        const float p = (dj <= 1024) ? __expf(s) : 0.f;
        rden[r] += p;
        Ps[(il * 8 + ((jl >> 3) ^ (il & 7))) * 8 + (jl & 7)] = f2bf(p);
      }
    }

    // ---- O += P @ V (wave-private P strip; no barrier needed) ----
#pragma unroll
    for (int ks = 0; ks < 2; ++ks) {
      const int frp = wv * 16 + l15;
      const int cp = (ks * 4 + quad) ^ (frp & 7);
      const short8 pf = *(const short8*)(smem + (frp * 8 + cp) * 16);
#pragma unroll
      for (int dt = 0; dt < 4; ++dt) {
        const int vr = dt * 16 + l15;
        const int vc = (ks * 4 + quad) ^ (vr & 7);
        const short8 vf = *(const short8*)(smem + 8192 + (vr * 8 + vc) * 16);
        O[dt] = __builtin_amdgcn_mfma_f32_16x16x32_bf16(pf, vf, O[dt], 0, 0, 0);
      }
    }
  }

  // denominator: reduce across the 16 lanes of each quad
#pragma unroll
  for (int m = 1; m < 16; m <<= 1)
#pragma unroll
    for (int r = 0; r < 4; ++r)
      rden[r] += __shfl_xor(rden[r], m, 64);

  // normalize, write AVb[q][b][n][d] bf16
#pragma unroll
  for (int r = 0; r < 4; ++r) {
    const float inv = 1.f / rden[r];
    const int ig = i0 + wv * 16 + quad * 4 + r;
#pragma unroll
    for (int dt = 0; dt < 4; ++dt)
      AVb[((size_t)ig * BSZ + b) * DMODEL + n * DHEAD + dt * 16 + l15] =
          f2bf(O[dt][r] * inv);
  }
}

// ---------------------------------------------------------------------------
__global__ __launch_bounds__(256) void ln_kernel(
    float* __restrict__ X, const float* __restrict__ gw,
    const float* __restrict__ bw, unsigned short* __restrict__ bfo)
{
  const int row = blockIdx.x, tid = threadIdx.x;
  float* rp = X + (size_t)row * DMODEL;
  const float4 x = *(const float4*)(rp + tid * 4);
  float s = x.x + x.y + x.z + x.w;
  float q = x.x * x.x + x.y * x.y + x.z * x.z + x.w * x.w;
#pragma unroll
  for (int m = 1; m < 64; m <<= 1) {
    s += __shfl_xor(s, m, 64);
    q += __shfl_xor(q, m, 64);
  }
  __shared__ float ss[4], sq[4];
  if ((tid & 63) == 0) { ss[tid >> 6] = s; sq[tid >> 6] = q; }
  __syncthreads();
  s = ss[0] + ss[1] + ss[2] + ss[3];
  q = sq[0] + sq[1] + sq[2] + sq[3];
  const float mu = s * (1.f / DMODEL);
  const float var = q * (1.f / DMODEL) - mu * mu;
  const float rstd = rsqrtf(var + 1e-5f);
  const float4 g4 = *(const float4*)(gw + tid * 4);
  const float4 b4 = *(const float4*)(bw + tid * 4);
  float4 y;
  y.x = (x.x - mu) * rstd * g4.x + b4.x;
  y.y = (x.y - mu) * rstd * g4.y + b4.y;
  y.z = (x.z - mu) * rstd * g4.z + b4.z;
  y.w = (x.w - mu) * rstd * g4.w + b4.w;
  *(float4*)(rp + tid * 4) = y;
  if (bfo) {
    short4_t o;
    o[0] = (short)f2bf(y.x); o[1] = (short)f2bf(y.y);
    o[2] = (short)f2bf(y.z); o[3] = (short)f2bf(y.w);
    *(short4_t*)(bfo + (size_t)row * DMODEL + tid * 4) = o;
  }
}

// ---------------------------------------------------------------------------
extern "C" void kernel_launch(void* const* d_in, const int* in_sizes, int n_in,
                              void* d_out, int out_size, void* d_ws,
                              size_t ws_size, hipStream_t stream)
{
  const float* w       = (const float*)d_in[0];
  const float* r       = (const float*)d_in[1];
  const float* mems    = (const float*)d_in[2];
  const float* r_w_bias= (const float*)d_in[6];
  const float* r_r_bias= (const float*)d_in[7];
  const float* ln1_g   = (const float*)d_in[8];
  const float* ln1_b   = (const float*)d_in[9];
  const float* ff_b1   = (const float*)d_in[11];
  const float* ff_b2   = (const float*)d_in[13];
  const float* ln2_g   = (const float*)d_in[14];
  const float* ln2_b   = (const float*)d_in[15];
  const float* qkv_w   = (const float*)d_in[3];
  const float* r_net_w = (const float*)d_in[4];
  const float* o_w     = (const float*)d_in[5];
  const float* ff_w1   = (const float*)d_in[10];
  const float* ff_w2   = (const float*)d_in[12];
  float* out = (float*)d_out;

  // ---- workspace carve-up ----
  float* X1 = (float*)d_ws;                               // 4,194,304 f32
  unsigned short* Qh   = (unsigned short*)(X1 + 4194304); // 4,194,304
  unsigned short* Kh   = Qh + 4194304;                    // 8,388,608
  unsigned short* Vt   = Kh + 8388608;                    // 8,388,608
  unsigned short* Rk   = Vt + 8388608;                    // 2,097,152 (+8192 pad)
  unsigned short* Xcat = Rk + 2097152 + 8192;             // 8,388,608
  unsigned short* Wqkv = Xcat + 8388608;                  // 3,145,728
  unsigned short* Wr   = Wqkv + 3145728;                  // 1,048,576
  unsigned short* Wo   = Wr + 1048576;                    // 1,048,576
  unsigned short* W1   = Wo + 1048576;                    // 4,194,304
  unsigned short* W2   = W1 + 4194304;                    // 4,194,304
  unsigned short* Rb16 = Xcat;                 // alias (Xcat dead after qkv)
  unsigned short* AVb  = Xcat + 4194304;       // alias, disjoint from Rb16
  unsigned short* X1b  = Qh;                   // alias (Qh dead after attn)
  unsigned short* H    = Kh;                   // alias (spans Kh+Vt, 16.8M)

  const dim3 blk(256);

  cast_bf16<<<dim3(2048), blk, 0, stream>>>(mems, Xcat);
  cast_bf16<<<dim3(2048), blk, 0, stream>>>(w, Xcat + 4194304);
  transpose_cast<<<dim3(48, 16), blk, 0, stream>>>(qkv_w, Wqkv, 1024, 3072);
  transpose_cast<<<dim3(16, 16), blk, 0, stream>>>(r_net_w, Wr, 1024, 1024);
  transpose_cast<<<dim3(16, 16), blk, 0, stream>>>(o_w, Wo, 1024, 1024);
  transpose_cast<<<dim3(64, 16), blk, 0, stream>>>(ff_w1, W1, 1024, 4096);
  transpose_cast<<<dim3(16, 64), blk, 0, stream>>>(ff_w2, W2, 4096, 1024);

  // 1. QKV: [8192,1024]@[1024,3072] -> Qh/Kh/Vt bf16
  mgemm<0><<<dim3(24, 64), blk, 0, stream>>>(
      Xcat, Wqkv, nullptr, Qh, nullptr, nullptr, Kh, Vt, DMODEL, 3 * DMODEL);
  // 2. R projection -> Rk bf16
  cast_bf16<<<dim3(1024), blk, 0, stream>>>(r, Rb16);
  mgemm<1><<<dim3(8, 16), blk, 0, stream>>>(
      Rb16, Wr, nullptr, Rk, nullptr, nullptr, nullptr, nullptr, DMODEL, DMODEL);
  // 3. MFMA flash attention -> AVb bf16
  attn_mfma<<<dim3(16, 64), blk, 0, stream>>>(
      Qh, Kh, Vt, Rk, r_w_bias, r_r_bias, AVb);
  // 4. o-proj + residual -> X1 fp32; LN1 (+X1b bf16)
  mgemm<2><<<dim3(8, 32), blk, 0, stream>>>(
      AVb, Wo, X1, nullptr, nullptr, w, nullptr, nullptr, DMODEL, DMODEL);
  ln_kernel<<<dim3(4096), blk, 0, stream>>>(X1, ln1_g, ln1_b, X1b);
  // 5. FFN up + relu -> H bf16
  mgemm<3><<<dim3(32, 32), blk, 0, stream>>>(
      X1b, W1, nullptr, H, ff_b1, nullptr, nullptr, nullptr, DMODEL, DINNER);
  // 6. FFN down + bias + residual -> out fp32; LN2
  mgemm<4><<<dim3(8, 32), blk, 0, stream>>>(
      H, W2, out, nullptr, ff_b2, X1, nullptr, nullptr, DINNER, DMODEL);
  ln_kernel<<<dim3(4096), blk, 0, stream>>>(out, ln2_g, ln2_b, nullptr);

  (void)in_sizes; (void)n_in; (void)out_size; (void)ws_size;
}

// Round 4
// 660.370 us; speedup vs baseline: 4.8128x; 1.0387x over previous
//
#include <hip/hip_runtime.h>
#include <math.h>

// ---------------------------------------------------------------------------
// MemTransformerLM (Transformer-XL layer) — round 4.
// Changes vs r3: attn uses banded-U (5 tt-tiles/wave, U in regs, Us aliases
// R region -> 32KB LDS, 4-5 blocks/CU); V written row-major by mgemm<0> and
// transposed by a dedicated coalesced kernel (Vh borrows X1's 16MB).
// ---------------------------------------------------------------------------

#define QLEN 1024
#define BSZ  4
#define DMODEL 1024
#define NHEAD 16
#define DHEAD 64
#define DINNER 4096
#define MEMLEN 1024
#define KLEN 2048

typedef __attribute__((ext_vector_type(8))) short short8;
typedef __attribute__((ext_vector_type(4))) short short4_t;
typedef __attribute__((ext_vector_type(4))) float f32x4;

__device__ __forceinline__ unsigned short f2bf(float x) {
  union { float f; unsigned u; } cv; cv.f = x;
  const unsigned u = cv.u;
  return (unsigned short)((u + 0x7FFFu + ((u >> 16) & 1u)) >> 16);
}
__device__ __forceinline__ float bf2f(unsigned short b) {
  union { unsigned u; float f; } cv; cv.u = ((unsigned)b) << 16;
  return cv.f;
}

__device__ __forceinline__ void gload16(const void* g, void* l) {
  __builtin_amdgcn_global_load_lds(
      (const __attribute__((address_space(1))) unsigned int*)g,
      (__attribute__((address_space(3))) unsigned int*)l, 16, 0, 0);
}

__device__ __forceinline__ int chidx(int row, int kc) {
  return row * 4 + (kc ^ ((row >> 1) & 3));
}

// ---------------------------------------------------------------------------
// bf16 MFMA GEMM: C[M,N] = A[M,K] @ Bt[N,K]^T. 128x128 tile, BK=32, 4 waves.
// MODE 0: qkv scatter -> Cb(Qh bf16), oK(Kh bf16), oV(Vh bf16 ROW-MAJOR)
// MODE 1: rproj scatter -> Cb(Rk bf16)
// MODE 2: C fp32 = acc + res[row,col]
// MODE 3: Cb bf16 = relu(acc + aux[col])
// MODE 4: C fp32 = acc + aux[col] + res[row,col]
// ---------------------------------------------------------------------------
template<int MODE>
__global__ __launch_bounds__(256) void mgemm(
    const unsigned short* __restrict__ A, const unsigned short* __restrict__ Bt,
    float* __restrict__ C, unsigned short* __restrict__ Cb,
    const float* __restrict__ aux, const float* __restrict__ res,
    unsigned short* __restrict__ oK, unsigned short* __restrict__ oV,
    int Kdim, int N)
{
  __shared__ __align__(16) char smem[16384];   // A 8KB | B 8KB

  const int tid = threadIdx.x;
  const int lane = tid & 63, wv = tid >> 6;
  const int m0 = (int)blockIdx.y * 128, n0 = (int)blockIdx.x * 128;

  const unsigned short *gA0, *gA1, *gB0, *gB1;
  {
    int c = tid, m = c >> 2, kc = (c & 3) ^ ((m >> 1) & 3);
    gA0 = A + (size_t)(m0 + m) * Kdim + kc * 8;
    c = 256 + tid; m = c >> 2; kc = (c & 3) ^ ((m >> 1) & 3);
    gA1 = A + (size_t)(m0 + m) * Kdim + kc * 8;
    c = tid; int nn = c >> 2; kc = (c & 3) ^ ((nn >> 1) & 3);
    gB0 = Bt + (size_t)(n0 + nn) * Kdim + kc * 8;
    c = 256 + tid; nn = c >> 2; kc = (c & 3) ^ ((nn >> 1) & 3);
    gB1 = Bt + (size_t)(n0 + nn) * Kdim + kc * 8;
  }
  char* const lds0 = smem + (tid & 192) * 16;

  const int fr = lane & 15, kq = lane >> 4;
  int aoff[4], boff[4];
#pragma unroll
  for (int t = 0; t < 4; ++t) {
    const int ra = (wv & 1) * 64 + t * 16 + fr;
    aoff[t] = chidx(ra, kq) * 16;
    const int rb = (wv >> 1) * 64 + t * 16 + fr;
    boff[t] = 8192 + chidx(rb, kq) * 16;
  }

  f32x4 acc[4][4] = {};

  for (int k0 = 0; k0 < Kdim; k0 += 32) {
    gload16(gA0, lds0);
    gload16(gA1, lds0 + 4096);
    gload16(gB0, lds0 + 8192);
    gload16(gB1, lds0 + 12288);
    gA0 += 32; gA1 += 32; gB0 += 32; gB1 += 32;
    __syncthreads();

    short8 af[4], bf[4];
#pragma unroll
    for (int t = 0; t < 4; ++t) af[t] = *(const short8*)(smem + aoff[t]);
#pragma unroll
    for (int t = 0; t < 4; ++t) bf[t] = *(const short8*)(smem + boff[t]);
#pragma unroll
    for (int i = 0; i < 4; ++i)
#pragma unroll
      for (int j = 0; j < 4; ++j)
        acc[i][j] = __builtin_amdgcn_mfma_f32_16x16x32_bf16(
            af[i], bf[j], acc[i][j], 0, 0, 0);
    __syncthreads();
  }

  const int rbase = m0 + (wv & 1) * 64 + (lane >> 4) * 4;
  const int cbase = n0 + (wv >> 1) * 64 + (lane & 15);
#pragma unroll
  for (int i = 0; i < 4; ++i) {
#pragma unroll
    for (int r = 0; r < 4; ++r) {
      const int grow = rbase + i * 16 + r;
#pragma unroll
      for (int j = 0; j < 4; ++j) {
        const int gcol = cbase + j * 16;
        const float v = acc[i][j][r];
        if constexpr (MODE == 0) {
          const int kkg = grow >> 2, b2 = grow & 3;
          const int sec = gcol >> 10, hn = (gcol >> 6) & 15, d = gcol & 63;
          const unsigned short bv = f2bf(v);
          if (sec == 0) {
            if (kkg >= MEMLEN)
              Cb[((size_t)(b2 * NHEAD + hn) * QLEN + (kkg - MEMLEN)) * DHEAD + d] = bv;
          } else if (sec == 1) {
            oK[((size_t)(b2 * NHEAD + hn) * KLEN + kkg) * DHEAD + d] = bv;
          } else {  // V row-major (transposed later by transpose_v)
            oV[((size_t)(b2 * NHEAD + hn) * KLEN + kkg) * DHEAD + d] = bv;
          }
        } else if constexpr (MODE == 1) {
          const int hn = gcol >> 6, d = gcol & 63;
          Cb[((size_t)hn * KLEN + grow) * DHEAD + d] = f2bf(v);
        } else if constexpr (MODE == 2) {
          C[(size_t)grow * N + gcol] = v + res[(size_t)grow * N + gcol];
        } else if constexpr (MODE == 3) {
          Cb[(size_t)grow * N + gcol] = f2bf(fmaxf(v + aux[gcol], 0.f));
        } else {
          C[(size_t)grow * N + gcol] = v + aux[gcol] + res[(size_t)grow * N + gcol];
        }
      }
    }
  }
}

// ---------------------------------------------------------------------------
// Vh [bn][j=2048][d=64] bf16 -> Vt [bn][d=64][j=2048]. grid (32 j-tiles, 64 bn).
// Coalesced global loads+stores; LDS 64x80-stride tile.
// ---------------------------------------------------------------------------
__global__ __launch_bounds__(256) void transpose_v(
    const unsigned short* __restrict__ Vh, unsigned short* __restrict__ Vt)
{
  __shared__ unsigned short t[64 * 80];
  const int j0 = (int)blockIdx.x * 64;
  const int bn = (int)blockIdx.y;
  const int tid = threadIdx.x;
#pragma unroll
  for (int it = 0; it < 2; ++it) {
    const int f = it * 256 + tid;
    const int j = f >> 3, d8 = (f & 7) * 8;
    const short8 v = *(const short8*)(Vh + ((size_t)bn * KLEN + j0 + j) * DHEAD + d8);
    *(short8*)(t + j * 80 + d8) = v;
  }
  __syncthreads();
  const int d = tid >> 2, jseg = (tid & 3) * 16;
  short8 o0, o1;
#pragma unroll
  for (int e = 0; e < 8; ++e) o0[e] = (short)t[(jseg + e) * 80 + d];
#pragma unroll
  for (int e = 0; e < 8; ++e) o1[e] = (short)t[(jseg + 8 + e) * 80 + d];
  unsigned short* op = Vt + ((size_t)bn * DHEAD + d) * KLEN + j0 + jseg;
  *(short8*)op = o0;
  *(short8*)(op + 8) = o1;
}

// ---------------------------------------------------------------------------
__global__ __launch_bounds__(256) void cast_bf16(
    const float* __restrict__ in, unsigned short* __restrict__ out)
{
  const size_t i = ((size_t)blockIdx.x * 256 + threadIdx.x) * 8;
  const float4 a = *(const float4*)(in + i);
  const float4 b = *(const float4*)(in + i + 4);
  short8 v;
  v[0] = (short)f2bf(a.x); v[1] = (short)f2bf(a.y);
  v[2] = (short)f2bf(a.z); v[3] = (short)f2bf(a.w);
  v[4] = (short)f2bf(b.x); v[5] = (short)f2bf(b.y);
  v[6] = (short)f2bf(b.z); v[7] = (short)f2bf(b.w);
  *(short8*)(out + i) = v;
}

// ---------------------------------------------------------------------------
__global__ __launch_bounds__(256) void transpose_cast(
    const float* __restrict__ in, unsigned short* __restrict__ out,
    int R, int C)
{
  __shared__ float t[64][65];
  const int r0 = (int)blockIdx.y * 64, c0 = (int)blockIdx.x * 64;
  const int tid = threadIdx.x;
  const int rr = tid >> 4, cc = (tid & 15) * 4;
#pragma unroll
  for (int it = 0; it < 4; ++it) {
    const int r = rr + it * 16;
    const float4 v = *(const float4*)(in + (size_t)(r0 + r) * C + c0 + cc);
    t[r][cc] = v.x; t[r][cc + 1] = v.y; t[r][cc + 2] = v.z; t[r][cc + 3] = v.w;
  }
  __syncthreads();
  const int oc = tid >> 2, ob = (tid & 3) * 16;
#pragma unroll
  for (int j4 = 0; j4 < 4; ++j4) {
    short4_t o;
#pragma unroll
    for (int j = 0; j < 4; ++j) o[j] = (short)f2bf(t[ob + j4 * 4 + j][oc]);
    *(short4_t*)(out + (size_t)(c0 + oc) * R + r0 + ob + j4 * 4) = o;
  }
}

// ---------------------------------------------------------------------------
// MFMA flash relative attention, banded-U version.
// Block = 4 waves; i-tile 64 (wave w owns rows [w*16, w*16+16)); j chunks 64.
// LDS 32KB: Ks 8K (Ps aliases) | Vts 8K | Rs 16K (Us aliases, banded 64x72).
// Per wave: 5 U t-tiles (tt = 3-wv .. 7-wv) cover exactly the needed band.
// ---------------------------------------------------------------------------
__global__ __launch_bounds__(256) void attn_mfma(
    const unsigned short* __restrict__ Qh, const unsigned short* __restrict__ Kh,
    const unsigned short* __restrict__ Vt, const unsigned short* __restrict__ Rk,
    const float* __restrict__ rwb, const float* __restrict__ rrb,
    unsigned short* __restrict__ AVb)
{
  __shared__ __align__(16) char smem[32768];
  unsigned short* const Us = (unsigned short*)(smem + 16384);  // banded, stride 72
  unsigned short* const Ps = (unsigned short*)smem;            // aliases Ks

  const int tid = threadIdx.x;
  const int lane = tid & 63, wv = tid >> 6;
  const int quad = lane >> 4, l15 = lane & 15;
  const int i0 = (int)blockIdx.x * 64;
  const int bn = (int)blockIdx.y, b = bn >> 4, n = bn & 15;

  const unsigned short* __restrict__ Qb = Qh + (size_t)bn * QLEN * DHEAD;
  const unsigned short* __restrict__ Kb = Kh + (size_t)bn * KLEN * DHEAD;
  const unsigned short* __restrict__ Vb = Vt + (size_t)bn * DHEAD * KLEN;
  const unsigned short* __restrict__ Rb = Rk + (size_t)n * KLEN * DHEAD;

  // persistent Q fragments with biases folded
  short8 qk[2], qr[2];
  {
    const int qrow = i0 + wv * 16 + l15;
    const unsigned short* qp = Qb + (size_t)qrow * DHEAD + quad * 8;
    const float* wp = rwb + n * DHEAD + quad * 8;
    const float* rp = rrb + n * DHEAD + quad * 8;
#pragma unroll
    for (int ks = 0; ks < 2; ++ks) {
      const short8 q8 = *(const short8*)(qp + ks * 32);
#pragma unroll
      for (int e = 0; e < 8; ++e) {
        const float qv = bf2f((unsigned short)q8[e]);
        qk[ks][e] = (short)f2bf(qv + wp[ks * 32 + e]);
        qr[ks][e] = (short)f2bf(qv + rp[ks * 32 + e]);
      }
    }
  }

  f32x4 O[4] = {};
  float rden[4] = {0.f, 0.f, 0.f, 0.f};
  char* const lds0 = smem + (tid & 192) * 16;
  const int nch = (i0 >> 6) + 17;
  const int tt0 = 3 - wv;

  for (int ch = 0; ch < nch; ++ch) {
    const int j0 = ch * 64;
    const int base_r = j0 - i0 + 960;   // >= 0; rows >= KLEN read pad (masked)

    __syncthreads();   // prior chunk's LDS reads complete before restage

    // ---- stage K (8KB @0), Vt (8KB @8192), R (16KB @16384) ----
#pragma unroll
    for (int it = 0; it < 2; ++it) {
      const int s = it * 256 + tid;
      const int row = s >> 3, kc = (s & 7) ^ (row & 7);
      gload16(Kb + (((size_t)(j0 + row)) << 6) + kc * 8, lds0 + it * 4096);
    }
#pragma unroll
    for (int it = 0; it < 2; ++it) {
      const int s = it * 256 + tid;
      const int row = s >> 3, kc = (s & 7) ^ (row & 7);
      gload16(Vb + (((size_t)row) << 11) + j0 + kc * 8, lds0 + 8192 + it * 4096);
    }
#pragma unroll
    for (int it = 0; it < 4; ++it) {
      const int s = it * 256 + tid;
      const int row = s >> 3, kc = (s & 7) ^ (row & 7);
      gload16(Rb + (((size_t)(base_r + row)) << 6) + kc * 8,
              lds0 + 16384 + it * 4096);
    }
    __syncthreads();

    // ---- S_K = (q+rwb)·k : 4 j-tiles ----
    f32x4 sk[4];
#pragma unroll
    for (int jt = 0; jt < 4; ++jt) {
      f32x4 a = {0.f, 0.f, 0.f, 0.f};
#pragma unroll
      for (int ks = 0; ks < 2; ++ks) {
        const int frr = jt * 16 + l15;
        const int c = (ks * 4 + quad) ^ (frr & 7);
        const short8 kf = *(const short8*)(smem + (frr * 8 + c) * 16);
        a = __builtin_amdgcn_mfma_f32_16x16x32_bf16(qk[ks], kf, a, 0, 0, 0);
      }
      sk[jt] = a;
    }
    // ---- U = (q+rrb)·r, banded: 5 t-tiles per wave, into registers ----
    f32x4 uu[5];
#pragma unroll
    for (int s = 0; s < 5; ++s) {
      f32x4 a = {0.f, 0.f, 0.f, 0.f};
      const int frr = (tt0 + s) * 16 + l15;
#pragma unroll
      for (int ks = 0; ks < 2; ++ks) {
        const int c = (ks * 4 + quad) ^ (frr & 7);
        const short8 rf = *(const short8*)(smem + 16384 + (frr * 8 + c) * 16);
        a = __builtin_amdgcn_mfma_f32_16x16x32_bf16(qr[ks], rf, a, 0, 0, 0);
      }
      uu[s] = a;
    }
    __syncthreads();   // all frag reads done; Us may overwrite Rs, Ps over Ks

    // ---- write banded U (wave-private strip): Us[il][jl] = U[il][jl-il+63] ----
#pragma unroll
    for (int s = 0; s < 5; ++s) {
      const int t = (tt0 + s) * 16 + l15;
#pragma unroll
      for (int r = 0; r < 4; ++r) {
        const int il = wv * 16 + quad * 4 + r;
        const int jl = t + il - 63;
        if (jl >= 0 && jl < 64) Us[il * 72 + jl] = f2bf(uu[s][r]);
      }
    }

    // ---- P = exp((S_K + U) * 1/8), masked; write Ps (A-layout) ----
#pragma unroll
    for (int jt = 0; jt < 4; ++jt) {
      const int jl = jt * 16 + l15;
#pragma unroll
      for (int r = 0; r < 4; ++r) {
        const int il = wv * 16 + quad * 4 + r;
        const int dj = (j0 + jl) - (i0 + il);
        const float uv = bf2f(Us[il * 72 + jl]);
        const float s = (sk[jt][r] + uv) * 0.125f;
        const float p = (dj <= 1024) ? __expf(s) : 0.f;
        rden[r] += p;
        Ps[(il * 8 + ((jl >> 3) ^ (il & 7))) * 8 + (jl & 7)] = f2bf(p);
      }
    }

    // ---- O += P @ V (wave-private P strip) ----
#pragma unroll
    for (int ks = 0; ks < 2; ++ks) {
      const int frp = wv * 16 + l15;
      const int cp = (ks * 4 + quad) ^ (frp & 7);
      const short8 pf = *(const short8*)(smem + (frp * 8 + cp) * 16);
#pragma unroll
      for (int dt = 0; dt < 4; ++dt) {
        const int vr = dt * 16 + l15;
        const int vc = (ks * 4 + quad) ^ (vr & 7);
        const short8 vf = *(const short8*)(smem + 8192 + (vr * 8 + vc) * 16);
        O[dt] = __builtin_amdgcn_mfma_f32_16x16x32_bf16(pf, vf, O[dt], 0, 0, 0);
      }
    }
  }

  // denominator: reduce across the 16 lanes of each quad
#pragma unroll
  for (int m = 1; m < 16; m <<= 1)
#pragma unroll
    for (int r = 0; r < 4; ++r)
      rden[r] += __shfl_xor(rden[r], m, 64);

  // normalize, write AVb[q][b][n][d] bf16
#pragma unroll
  for (int r = 0; r < 4; ++r) {
    const float inv = 1.f / rden[r];
    const int ig = i0 + wv * 16 + quad * 4 + r;
#pragma unroll
    for (int dt = 0; dt < 4; ++dt)
      AVb[((size_t)ig * BSZ + b) * DMODEL + n * DHEAD + dt * 16 + l15] =
          f2bf(O[dt][r] * inv);
  }
}

// ---------------------------------------------------------------------------
__global__ __launch_bounds__(256) void ln_kernel(
    float* __restrict__ X, const float* __restrict__ gw,
    const float* __restrict__ bw, unsigned short* __restrict__ bfo)
{
  const int row = blockIdx.x, tid = threadIdx.x;
  float* rp = X + (size_t)row * DMODEL;
  const float4 x = *(const float4*)(rp + tid * 4);
  float s = x.x + x.y + x.z + x.w;
  float q = x.x * x.x + x.y * x.y + x.z * x.z + x.w * x.w;
#pragma unroll
  for (int m = 1; m < 64; m <<= 1) {
    s += __shfl_xor(s, m, 64);
    q += __shfl_xor(q, m, 64);
  }
  __shared__ float ss[4], sq[4];
  if ((tid & 63) == 0) { ss[tid >> 6] = s; sq[tid >> 6] = q; }
  __syncthreads();
  s = ss[0] + ss[1] + ss[2] + ss[3];
  q = sq[0] + sq[1] + sq[2] + sq[3];
  const float mu = s * (1.f / DMODEL);
  const float var = q * (1.f / DMODEL) - mu * mu;
  const float rstd = rsqrtf(var + 1e-5f);
  const float4 g4 = *(const float4*)(gw + tid * 4);
  const float4 b4 = *(const float4*)(bw + tid * 4);
  float4 y;
  y.x = (x.x - mu) * rstd * g4.x + b4.x;
  y.y = (x.y - mu) * rstd * g4.y + b4.y;
  y.z = (x.z - mu) * rstd * g4.z + b4.z;
  y.w = (x.w - mu) * rstd * g4.w + b4.w;
  *(float4*)(rp + tid * 4) = y;
  if (bfo) {
    short4_t o;
    o[0] = (short)f2bf(y.x); o[1] = (short)f2bf(y.y);
    o[2] = (short)f2bf(y.z); o[3] = (short)f2bf(y.w);
    *(short4_t*)(bfo + (size_t)row * DMODEL + tid * 4) = o;
  }
}

// ---------------------------------------------------------------------------
extern "C" void kernel_launch(void* const* d_in, const int* in_sizes, int n_in,
                              void* d_out, int out_size, void* d_ws,
                              size_t ws_size, hipStream_t stream)
{
  const float* w       = (const float*)d_in[0];
  const float* r       = (const float*)d_in[1];
  const float* mems    = (const float*)d_in[2];
  const float* qkv_w   = (const float*)d_in[3];
  const float* r_net_w = (const float*)d_in[4];
  const float* o_w     = (const float*)d_in[5];
  const float* r_w_bias= (const float*)d_in[6];
  const float* r_r_bias= (const float*)d_in[7];
  const float* ln1_g   = (const float*)d_in[8];
  const float* ln1_b   = (const float*)d_in[9];
  const float* ff_w1   = (const float*)d_in[10];
  const float* ff_b1   = (const float*)d_in[11];
  const float* ff_w2   = (const float*)d_in[12];
  const float* ff_b2   = (const float*)d_in[13];
  const float* ln2_g   = (const float*)d_in[14];
  const float* ln2_b   = (const float*)d_in[15];
  float* out = (float*)d_out;

  // ---- workspace carve-up ----
  float* X1 = (float*)d_ws;                               // 4,194,304 f32
  unsigned short* Qh   = (unsigned short*)(X1 + 4194304); // 4,194,304 bf16
  unsigned short* Kh   = Qh + 4194304;                    // 8,388,608
  unsigned short* Vt   = Kh + 8388608;                    // 8,388,608
  unsigned short* Rk   = Vt + 8388608;                    // 2,097,152 (+8192 pad)
  unsigned short* Xcat = Rk + 2097152 + 8192;             // 8,388,608
  unsigned short* Wqkv = Xcat + 8388608;                  // 3,145,728
  unsigned short* Wr   = Wqkv + 3145728;                  // 1,048,576
  unsigned short* Wo   = Wr + 1048576;                    // 1,048,576
  unsigned short* W1   = Wo + 1048576;                    // 4,194,304
  unsigned short* W2   = W1 + 4194304;                    // 4,194,304
  unsigned short* Vh   = (unsigned short*)X1;  // borrow X1 (dead until oproj) — exact 16MB fit
  unsigned short* Rb16 = Xcat;                 // alias (Xcat dead after qkv)
  unsigned short* AVb  = Xcat + 4194304;       // alias, disjoint from Rb16
  unsigned short* X1b  = Qh;                   // alias (Qh dead after attn)
  unsigned short* H    = Kh;                   // alias (spans Kh+Vt, 16.8M)

  const dim3 blk(256);

  cast_bf16<<<dim3(2048), blk, 0, stream>>>(mems, Xcat);
  cast_bf16<<<dim3(2048), blk, 0, stream>>>(w, Xcat + 4194304);
  transpose_cast<<<dim3(48, 16), blk, 0, stream>>>(qkv_w, Wqkv, 1024, 3072);
  transpose_cast<<<dim3(16, 16), blk, 0, stream>>>(r_net_w, Wr, 1024, 1024);
  transpose_cast<<<dim3(16, 16), blk, 0, stream>>>(o_w, Wo, 1024, 1024);
  transpose_cast<<<dim3(64, 16), blk, 0, stream>>>(ff_w1, W1, 1024, 4096);
  transpose_cast<<<dim3(16, 64), blk, 0, stream>>>(ff_w2, W2, 4096, 1024);

  // 1. QKV: [8192,1024]@[1024,3072] -> Qh/Kh bf16, Vh row-major bf16
  mgemm<0><<<dim3(24, 64), blk, 0, stream>>>(
      Xcat, Wqkv, nullptr, Qh, nullptr, nullptr, Kh, Vh, DMODEL, 3 * DMODEL);
  // 1b. transpose V: Vh [bn][j][d] -> Vt [bn][d][j]
  transpose_v<<<dim3(32, 64), blk, 0, stream>>>(Vh, Vt);
  // 2. R projection -> Rk bf16
  cast_bf16<<<dim3(1024), blk, 0, stream>>>(r, Rb16);
  mgemm<1><<<dim3(8, 16), blk, 0, stream>>>(
      Rb16, Wr, nullptr, Rk, nullptr, nullptr, nullptr, nullptr, DMODEL, DMODEL);
  // 3. MFMA flash attention -> AVb bf16
  attn_mfma<<<dim3(16, 64), blk, 0, stream>>>(
      Qh, Kh, Vt, Rk, r_w_bias, r_r_bias, AVb);
  // 4. o-proj + residual -> X1 fp32; LN1 (+X1b bf16)
  mgemm<2><<<dim3(8, 32), blk, 0, stream>>>(
      AVb, Wo, X1, nullptr, nullptr, w, nullptr, nullptr, DMODEL, DMODEL);
  ln_kernel<<<dim3(4096), blk, 0, stream>>>(X1, ln1_g, ln1_b, X1b);
  // 5. FFN up + relu -> H bf16
  mgemm<3><<<dim3(32, 32), blk, 0, stream>>>(
      X1b, W1, nullptr, H, ff_b1, nullptr, nullptr, nullptr, DMODEL, DINNER);
  // 6. FFN down + bias + residual -> out fp32; LN2
  mgemm<4><<<dim3(8, 32), blk, 0, stream>>>(
      H, W2, out, nullptr, ff_b2, X1, nullptr, nullptr, DINNER, DMODEL);
  ln_kernel<<<dim3(4096), blk, 0, stream>>>(out, ln2_g, ln2_b, nullptr);

  (void)in_sizes; (void)n_in; (void)out_size; (void)ws_size;
}